// Round 1
// baseline (4938.468 us; speedup 1.0000x reference)
//
#include <hip/hip_runtime.h>
#include <cmath>

typedef _Float16 f16;
typedef _Float16 half8 __attribute__((ext_vector_type(8)));
typedef float f32x4 __attribute__((ext_vector_type(4)));

#define M_TOTAL 32768   // B * C * T = 8 * 4096
#define D_MODEL 768
#define NE_TOT  25165824  // M_TOTAL * D_MODEL

// ---------------------------------------------------------------- utilities

__device__ __forceinline__ void async_copy16(void* lds, const void* gmem) {
  // global -> LDS direct DMA, 16B per lane. LDS dest is wave-uniform base +
  // lane*16; our chunk indexing is lane-contiguous so this matches.
  __builtin_amdgcn_global_load_lds(
      (__attribute__((address_space(1))) void*)gmem,
      (__attribute__((address_space(3))) void*)lds, 16, 0, 0);
}

__device__ __forceinline__ float gelu_exact(float v) {
  return 0.5f * v * (1.0f + erff(v * 0.70710678118654752f));
}

__device__ __forceinline__ float slot_scale(const unsigned* slot) {
  return fmaxf(__uint_as_float(*slot), 1e-8f) / 127.0f;
}

__device__ __forceinline__ float fq_val(float v, float s) {
  float q = fminf(fmaxf(rintf(v / s), -128.f), 127.f);
  return q * s;
}

// ---------------------------------------------------------------- small kernels

__global__ void zero_slots_k(unsigned* s) {
  if (threadIdx.x < 16) s[threadIdx.x] = 0u;
}

__global__ void absmax_k(const float* __restrict__ x, int n,
                         unsigned* __restrict__ slot) {
  int i = blockIdx.x * blockDim.x + threadIdx.x;
  int stride = gridDim.x * blockDim.x;
  float m = 0.f;
  for (; i < n; i += stride) m = fmaxf(m, fabsf(x[i]));
  for (int o = 32; o; o >>= 1) m = fmaxf(m, __shfl_down(m, o));
  if ((threadIdx.x & 63) == 0) atomicMax(slot, __float_as_uint(m));
}

__global__ void quant_w_k(const float* __restrict__ x, int n,
                          const unsigned* __restrict__ slot,
                          f16* __restrict__ out) {
  int i = blockIdx.x * blockDim.x + threadIdx.x;
  if (i >= n) return;
  float s = slot_scale(slot);
  out[i] = (f16)fq_val(x[i], s);
}

// LayerNorm pass 1: per-row mean/rstd + global absmax of normalized output
__global__ __launch_bounds__(256) void ln_stats_k(
    const float* __restrict__ x, const float* __restrict__ gw,
    const float* __restrict__ bw, float* __restrict__ rowstats,
    unsigned* __restrict__ slot) {
  int row = blockIdx.x, tid = threadIdx.x;
  const float* xr = x + (size_t)row * D_MODEL;
  float v0 = xr[tid], v1 = xr[tid + 256], v2 = xr[tid + 512];
  float s = v0 + v1 + v2;
  float ss = v0 * v0 + v1 * v1 + v2 * v2;
  for (int o = 32; o; o >>= 1) {
    s += __shfl_down(s, o);
    ss += __shfl_down(ss, o);
  }
  __shared__ float red[8];
  int lane = tid & 63, wv = tid >> 6;
  if (lane == 0) { red[wv] = s; red[4 + wv] = ss; }
  __syncthreads();
  float st = red[0] + red[1] + red[2] + red[3];
  float sst = red[4] + red[5] + red[6] + red[7];
  float mean = st * (1.f / 768.f);
  float var = sst * (1.f / 768.f) - mean * mean;
  float rstd = rsqrtf(var + 1e-5f);
  if (tid == 0) { rowstats[2 * row] = mean; rowstats[2 * row + 1] = rstd; }
  float y0 = (v0 - mean) * rstd * gw[tid] + bw[tid];
  float y1 = (v1 - mean) * rstd * gw[tid + 256] + bw[tid + 256];
  float y2 = (v2 - mean) * rstd * gw[tid + 512] + bw[tid + 512];
  float m = fmaxf(fabsf(y0), fmaxf(fabsf(y1), fabsf(y2)));
  for (int o = 32; o; o >>= 1) m = fmaxf(m, __shfl_down(m, o));
  if (lane == 0) atomicMax(slot, __float_as_uint(m));
}

// LayerNorm pass 2: recompute y from stored stats, fake-quant, emit f16
__global__ void ln_quant_k(const float* __restrict__ x,
                           const float* __restrict__ gw,
                           const float* __restrict__ bw,
                           const float* __restrict__ rowstats,
                           const unsigned* __restrict__ slot,
                           f16* __restrict__ out) {
  int i = blockIdx.x * blockDim.x + threadIdx.x;
  if (i >= NE_TOT) return;
  int row = i / D_MODEL, col = i - row * D_MODEL;
  float mean = rowstats[2 * row], rstd = rowstats[2 * row + 1];
  float y = (x[i] - mean) * rstd * gw[col] + bw[col];
  float s = slot_scale(slot);
  out[i] = (f16)fq_val(y, s);
}

// quantize attention output (strided read out of the qkv buffer's Q slice)
__global__ void quant_strided_k(const f16* __restrict__ src,
                                const unsigned* __restrict__ slot,
                                f16* __restrict__ out) {
  int i = blockIdx.x * blockDim.x + threadIdx.x;
  if (i >= NE_TOT) return;
  int row = i / D_MODEL, col = i - row * D_MODEL;
  float v = (float)src[(size_t)row * 2304 + col];
  float s = slot_scale(slot);
  out[i] = (f16)fq_val(v, s);
}

// in-place fake-quant of gelu output (f16 buffer)
__global__ void requant_k(f16* __restrict__ g, int n,
                          const unsigned* __restrict__ slot) {
  int i = blockIdx.x * blockDim.x + threadIdx.x;
  if (i >= n) return;
  float s = slot_scale(slot);
  g[i] = (f16)fq_val((float)g[i], s);
}

// ---------------------------------------------------------------- GEMM (BT)
// C[m,n] = sum_k A[m,k] * B[n,k] + bias[n] (+resid) (+gelu) ; 128x128 tile,
// BK=32, 4 waves of 64x64, mfma_f32_16x16x32_f16, global_load_lds staging.
__global__ __launch_bounds__(256) void gemm_k(
    const f16* __restrict__ A, const f16* __restrict__ B,
    const float* __restrict__ bias, const float* resid,
    float* outf, f16* outh, unsigned* amax_slot,
    int N, int K, int gelu_mode) {
  __shared__ __attribute__((aligned(16))) f16 sA[128 * 32];
  __shared__ __attribute__((aligned(16))) f16 sB[128 * 32];
  int tid = threadIdx.x;
  int n0 = blockIdx.x * 128, m0 = blockIdx.y * 128;
  int lane = tid & 63, wv = tid >> 6;
  int wm = (wv & 1) * 64, wn = (wv >> 1) * 64;
  int lr = lane & 15, quad = lane >> 4;

  f32x4 acc[4][4];
#pragma unroll
  for (int i = 0; i < 4; ++i)
#pragma unroll
    for (int j = 0; j < 4; ++j) acc[i][j] = f32x4{0.f, 0.f, 0.f, 0.f};

  for (int k0 = 0; k0 < K; k0 += 32) {
#pragma unroll
    for (int it = 0; it < 2; ++it) {
      int c = it * 256 + tid;      // 512 chunks of 16B per tile
      int r = c >> 2, kc = c & 3;  // row in tile, 16B-column
      async_copy16(&sA[c * 8], A + (size_t)(m0 + r) * K + k0 + kc * 8);
      async_copy16(&sB[c * 8], B + (size_t)(n0 + r) * K + k0 + kc * 8);
    }
    __syncthreads();  // drains vmcnt for the global_load_lds queue
    half8 af[4], bfv[4];
#pragma unroll
    for (int i = 0; i < 4; ++i)
      af[i] = *(const half8*)&sA[(wm + i * 16 + lr) * 32 + quad * 8];
#pragma unroll
    for (int j = 0; j < 4; ++j)
      bfv[j] = *(const half8*)&sB[(wn + j * 16 + lr) * 32 + quad * 8];
#pragma unroll
    for (int i = 0; i < 4; ++i)
#pragma unroll
      for (int j = 0; j < 4; ++j)
        acc[i][j] = __builtin_amdgcn_mfma_f32_16x16x32_f16(af[i], bfv[j],
                                                           acc[i][j], 0, 0, 0);
    __syncthreads();
  }

  // epilogue: C/D layout col=lane&15, row=quad*4+reg
  float lmax = 0.f;
#pragma unroll
  for (int i = 0; i < 4; ++i) {
    int r0 = m0 + wm + i * 16 + quad * 4;
#pragma unroll
    for (int j = 0; j < 4; ++j) {
      int col = n0 + wn + j * 16 + lr;
      float bv = bias[col];
#pragma unroll
      for (int reg = 0; reg < 4; ++reg) {
        size_t idx = (size_t)(r0 + reg) * N + col;
        float v = acc[i][j][reg] + bv;
        if (resid) v += resid[idx];
        if (gelu_mode) {
          v = gelu_exact(v);
          lmax = fmaxf(lmax, fabsf(v));
        }
        if (outf) outf[idx] = v;
        else outh[idx] = (f16)v;
      }
    }
  }
  if (amax_slot) {
    for (int o = 32; o; o >>= 1) lmax = fmaxf(lmax, __shfl_down(lmax, o));
    if (lane == 0) atomicMax(amax_slot, __float_as_uint(lmax));
  }
}

// ---------------------------------------------------------------- attention
// one block per (b, c, head): 64x64 scores, softmax, PV; writes o in place
// over the Q slice of the qkv buffer (only this block touches that slice).
__global__ __launch_bounds__(256) void attn_k(f16* __restrict__ qkv,
                                              unsigned* __restrict__ slot) {
  __shared__ float sQ[64][65];  // stride 65: kills 64-way bank conflicts
  __shared__ float sK[64][65];
  __shared__ float sV[64][65];
  int tid = threadIdx.x, lane = tid & 63, wv = tid >> 6;
  int blk = blockIdx.x;
  int h = blk % 12, bc = blk / 12;  // bc = b*64 + c
  size_t base = (size_t)bc * 64 * 2304;
  int qo = h * 64, ko = 768 + h * 64, vo = 1536 + h * 64;

  for (int idx = tid; idx < 4096; idx += 256) {
    int t = idx >> 6, d = idx & 63;
    size_t r = base + (size_t)t * 2304;
    sQ[t][d] = (float)qkv[r + qo + d];
    sK[t][d] = (float)qkv[r + ko + d];
    sV[t][d] = (float)qkv[r + vo + d];
  }
  __syncthreads();

  // scores: wave wv handles rows t = wv + 4*it, lane = key index s
  float p[16];
#pragma unroll
  for (int it = 0; it < 16; ++it) {
    int t = wv + 4 * it;
    float a = 0.f;
    for (int k = 0; k < 64; ++k) a += sQ[t][k] * sK[lane][k];
    p[it] = a * 0.125f;  // 1/sqrt(64)
  }
  // softmax per row: row lives across the 64 lanes of one wave
#pragma unroll
  for (int it = 0; it < 16; ++it) {
    float v = p[it], m = v;
    for (int o = 32; o; o >>= 1) m = fmaxf(m, __shfl_xor(m, o));
    float e = expf(v - m);
    float den = e;
    for (int o = 32; o; o >>= 1) den += __shfl_xor(den, o);
    p[it] = e / den;
  }
  __syncthreads();  // all score reads of sQ/sK done
#pragma unroll
  for (int it = 0; it < 16; ++it) sQ[wv + 4 * it][lane] = p[it];  // sQ := P
  __syncthreads();

  float lmax = 0.f;
  for (int idx = tid; idx < 4096; idx += 256) {
    int t = idx >> 6, d = idx & 63;
    float a = 0.f;
    for (int s2 = 0; s2 < 64; ++s2) a += sQ[t][s2] * sV[s2][d];
    qkv[base + (size_t)t * 2304 + qo + d] = (f16)a;
    lmax = fmaxf(lmax, fabsf(a));
  }
  for (int o = 32; o; o >>= 1) lmax = fmaxf(lmax, __shfl_down(lmax, o));
  if (lane == 0) atomicMax(slot, __float_as_uint(lmax));
}

// ---------------------------------------------------------------- launch

extern "C" void kernel_launch(void* const* d_in, const int* in_sizes, int n_in,
                              void* d_out, int out_size, void* d_ws,
                              size_t ws_size, hipStream_t stream) {
  (void)in_sizes; (void)n_in; (void)out_size; (void)ws_size;
  const float* x      = (const float*)d_in[0];
  const float* ln1_g  = (const float*)d_in[1];
  const float* ln1_b  = (const float*)d_in[2];
  const float* qkv_w  = (const float*)d_in[3];
  const float* qkv_b  = (const float*)d_in[4];
  const float* proj_w = (const float*)d_in[5];
  const float* proj_b = (const float*)d_in[6];
  const float* ln2_g  = (const float*)d_in[7];
  const float* ln2_b  = (const float*)d_in[8];
  const float* fc1_w  = (const float*)d_in[9];
  const float* fc1_b  = (const float*)d_in[10];
  const float* fc2_w  = (const float*)d_in[11];
  const float* fc2_b  = (const float*)d_in[12];
  float* out = (float*)d_out;

  char* ws = (char*)d_ws;
  unsigned* slots = (unsigned*)ws;             // 8 absmax slots
  float* rowstats = (float*)(ws + 256);        // 32768 x {mean, rstd}
  f16* qkv_wq  = (f16*)(ws + 262400);          // quantized weights (f16)
  f16* proj_wq = qkv_wq + 1769472;
  f16* fc1_wq  = proj_wq + 589824;
  f16* fc2_wq  = fc1_wq + 2359296;
  f16* hbuf    = fc2_wq + 2359296;             // 25165824 f16 (LN out / o_q)
  f16* big     = hbuf + 25165824;              // qkv f16 [M,2304] then g f16 [M,3072]
  // total ws use ≈ 254 MB

  zero_slots_k<<<1, 64, 0, stream>>>(slots);

  absmax_k<<<256, 256, 0, stream>>>(qkv_w, 1769472, slots + 1);
  absmax_k<<<256, 256, 0, stream>>>(proj_w, 589824, slots + 2);
  absmax_k<<<256, 256, 0, stream>>>(fc1_w, 2359296, slots + 3);
  absmax_k<<<256, 256, 0, stream>>>(fc2_w, 2359296, slots + 4);
  quant_w_k<<<(1769472 + 255) / 256, 256, 0, stream>>>(qkv_w, 1769472, slots + 1, qkv_wq);
  quant_w_k<<<(589824 + 255) / 256, 256, 0, stream>>>(proj_w, 589824, slots + 2, proj_wq);
  quant_w_k<<<(2359296 + 255) / 256, 256, 0, stream>>>(fc1_w, 2359296, slots + 3, fc1_wq);
  quant_w_k<<<(2359296 + 255) / 256, 256, 0, stream>>>(fc2_w, 2359296, slots + 4, fc2_wq);

  // LN1 -> fq -> hbuf
  ln_stats_k<<<32768, 256, 0, stream>>>(x, ln1_g, ln1_b, rowstats, slots + 0);
  ln_quant_k<<<NE_TOT / 256, 256, 0, stream>>>(x, ln1_g, ln1_b, rowstats, slots + 0, hbuf);
  // qkv = h @ qkv_w^T + b  -> big (f16 [M,2304])
  gemm_k<<<dim3(18, 256), 256, 0, stream>>>(hbuf, qkv_wq, qkv_b, nullptr,
                                            nullptr, big, nullptr, 2304, 768, 0);
  // attention in place (o -> Q slice of big)
  attn_k<<<6144, 256, 0, stream>>>(big, slots + 5);
  // fq(o) -> hbuf
  quant_strided_k<<<NE_TOT / 256, 256, 0, stream>>>(big, slots + 5, hbuf);
  // x2 = o_q @ proj_w^T + b + x  -> out
  gemm_k<<<dim3(6, 256), 256, 0, stream>>>(hbuf, proj_wq, proj_b, x,
                                           out, nullptr, nullptr, 768, 768, 0);
  // LN2 -> fq -> hbuf
  ln_stats_k<<<32768, 256, 0, stream>>>(out, ln2_g, ln2_b, rowstats, slots + 6);
  ln_quant_k<<<NE_TOT / 256, 256, 0, stream>>>(out, ln2_g, ln2_b, rowstats, slots + 6, hbuf);
  // g = gelu(h @ fc1_w^T + b) -> big (f16 [M,3072]) + absmax
  gemm_k<<<dim3(24, 256), 256, 0, stream>>>(hbuf, fc1_wq, fc1_b, nullptr,
                                            nullptr, big, slots + 7, 3072, 768, 1);
  // fq(g) in place
  requant_k<<<(100663296 + 255) / 256, 256, 0, stream>>>(big, 100663296, slots + 7);
  // out = g_q @ fc2_w^T + b + x2 (in-place residual on out)
  gemm_k<<<dim3(6, 256), 256, 0, stream>>>(big, fc2_wq, fc2_b, out,
                                           out, nullptr, nullptr, 768, 3072, 0);
}

// Round 2
// 1591.099 us; speedup vs baseline: 3.1038x; 3.1038x over previous
//
#include <hip/hip_runtime.h>
#include <cmath>

typedef _Float16 f16;
typedef _Float16 half8 __attribute__((ext_vector_type(8)));
typedef float f32x4 __attribute__((ext_vector_type(4)));

#define M_TOTAL 32768     // B * C * T = 8 * 4096
#define D_MODEL 768
#define NE_TOT  25165824  // M_TOTAL * D_MODEL
#define SPREAD_STRIDE 16  // unsigneds between atomic cells (64 B: own cache line)

// ---------------------------------------------------------------- utilities

__device__ __forceinline__ void async_copy16(void* lds, const void* gmem) {
  __builtin_amdgcn_global_load_lds(
      (__attribute__((address_space(1))) void*)gmem,
      (__attribute__((address_space(3))) void*)lds, 16, 0, 0);
}

__device__ __forceinline__ float gelu_exact(float v) {
  return 0.5f * v * (1.0f + erff(v * 0.70710678118654752f));
}

__device__ __forceinline__ float slot_scale(const unsigned* slot) {
  return fmaxf(__uint_as_float(*slot), 1e-8f) / 127.0f;
}

__device__ __forceinline__ float fq_val(float v, float s) {
  float q = fminf(fmaxf(rintf(v / s), -128.f), 127.f);
  return q * s;
}

// 256-thread block max reduction (4 waves)
__device__ __forceinline__ float block_reduce_max(float m) {
  __shared__ float red_brm[4];
  for (int o = 32; o; o >>= 1) m = fmaxf(m, __shfl_down(m, o));
  int lane = threadIdx.x & 63, wv = threadIdx.x >> 6;
  if (lane == 0) red_brm[wv] = m;
  __syncthreads();
  return fmaxf(fmaxf(red_brm[0], red_brm[1]), fmaxf(red_brm[2], red_brm[3]));
}

__device__ __forceinline__ unsigned* spread_cell(unsigned* spread, int slot,
                                                 int cell) {
  return spread + slot * 64 * SPREAD_STRIDE + (cell & 63) * SPREAD_STRIDE;
}

// ---------------------------------------------------------------- small kernels

__global__ void zero_spread_k(unsigned* s) {
  int i = blockIdx.x * blockDim.x + threadIdx.x;
  if (i < 8 * 64 * SPREAD_STRIDE) s[i] = 0u;
}

// 64-cell spread -> final slot value; wave w handles slot slot_lo + w
__global__ void reduce_slots_k(const unsigned* __restrict__ spread,
                               unsigned* __restrict__ finals, int slot_lo,
                               int n_slots) {
  int wv = threadIdx.x >> 6, lane = threadIdx.x & 63;
  if (wv >= n_slots) return;
  int slot = slot_lo + wv;
  float m = __uint_as_float(spread[slot * 64 * SPREAD_STRIDE + lane * SPREAD_STRIDE]);
  for (int o = 32; o; o >>= 1) m = fmaxf(m, __shfl_down(m, o));
  if (lane == 0) finals[slot] = __float_as_uint(m);
}

__global__ __launch_bounds__(256) void absmax_k(const float* __restrict__ x,
                                                int n4, unsigned* spread,
                                                int slot) {
  int i = blockIdx.x * blockDim.x + threadIdx.x;
  int stride = gridDim.x * blockDim.x;
  float m = 0.f;
  const float4* x4 = (const float4*)x;
  for (; i < n4; i += stride) {
    float4 v = x4[i];
    m = fmaxf(m, fmaxf(fmaxf(fabsf(v.x), fabsf(v.y)),
                       fmaxf(fabsf(v.z), fabsf(v.w))));
  }
  m = block_reduce_max(m);
  if (threadIdx.x == 0)
    atomicMax(spread_cell(spread, slot, blockIdx.x), __float_as_uint(m));
}

__global__ void quant_w_k(const float* __restrict__ x, int n,
                          const unsigned* __restrict__ slot,
                          f16* __restrict__ out) {
  int i = blockIdx.x * blockDim.x + threadIdx.x;
  if (i >= n) return;
  float s = slot_scale(slot);
  out[i] = (f16)fq_val(x[i], s);
}

// LayerNorm: write y (unquantized) as f16, accumulate global absmax of f32 y
__global__ __launch_bounds__(256) void ln_k(const float* __restrict__ x,
                                            const float* __restrict__ gw,
                                            const float* __restrict__ bw,
                                            f16* __restrict__ out,
                                            unsigned* spread, int slot) {
  int row = blockIdx.x, tid = threadIdx.x;
  const float* xr = x + (size_t)row * D_MODEL;
  float v0 = xr[tid], v1 = xr[tid + 256], v2 = xr[tid + 512];
  float s = v0 + v1 + v2;
  float ss = v0 * v0 + v1 * v1 + v2 * v2;
  for (int o = 32; o; o >>= 1) {
    s += __shfl_down(s, o);
    ss += __shfl_down(ss, o);
  }
  __shared__ float red[8];
  int lane = tid & 63, wv = tid >> 6;
  if (lane == 0) { red[wv] = s; red[4 + wv] = ss; }
  __syncthreads();
  float st = red[0] + red[1] + red[2] + red[3];
  float sst = red[4] + red[5] + red[6] + red[7];
  float mean = st * (1.f / 768.f);
  float var = sst * (1.f / 768.f) - mean * mean;
  float rstd = rsqrtf(var + 1e-5f);
  float y0 = (v0 - mean) * rstd * gw[tid] + bw[tid];
  float y1 = (v1 - mean) * rstd * gw[tid + 256] + bw[tid + 256];
  float y2 = (v2 - mean) * rstd * gw[tid + 512] + bw[tid + 512];
  f16* outr = out + (size_t)row * D_MODEL;
  outr[tid] = (f16)y0; outr[tid + 256] = (f16)y1; outr[tid + 512] = (f16)y2;
  float m = fmaxf(fabsf(y0), fmaxf(fabsf(y1), fabsf(y2)));
  __syncthreads();  // red[] done before helper's shared use
  m = block_reduce_max(m);
  if (tid == 0)
    atomicMax(spread_cell(spread, slot, blockIdx.x), __float_as_uint(m));
}

// in-place fake-quant of an f16 buffer, 8 elems/thread
__global__ void requant_k(f16* __restrict__ g, int n8,
                          const unsigned* __restrict__ slot) {
  int i = blockIdx.x * blockDim.x + threadIdx.x;
  if (i >= n8) return;
  float s = slot_scale(slot);
  half8 v = ((half8*)g)[i];
#pragma unroll
  for (int j = 0; j < 8; ++j) v[j] = (f16)fq_val((float)v[j], s);
  ((half8*)g)[i] = v;
}

// quantize attention output: strided read of Q slice of qkv buffer -> dense
__global__ void quant_strided_k(const f16* __restrict__ src,
                                const unsigned* __restrict__ slot,
                                f16* __restrict__ out) {
  int i = blockIdx.x * blockDim.x + threadIdx.x;  // 8-elem groups
  if (i >= NE_TOT / 8) return;
  int row = i / 96, c8 = i - row * 96;
  half8 v = *(const half8*)(src + (size_t)row * 2304 + c8 * 8);
  float s = slot_scale(slot);
#pragma unroll
  for (int j = 0; j < 8; ++j) v[j] = (f16)fq_val((float)v[j], s);
  ((half8*)out)[i] = v;
}

// ---------------------------------------------------------------- GEMM (BT)
// C[m,n] = sum_k A[m,k]*B[n,k] + bias[n] (+resid) (+gelu); 128x128 tile, BK=32,
// 4 waves of 64x64, mfma_f32_16x16x32_f16, global_load_lds width-16 staging.
__global__ __launch_bounds__(256) void gemm_k(
    const f16* __restrict__ A, const f16* __restrict__ B,
    const float* __restrict__ bias, const float* resid,
    float* outf, f16* outh, unsigned* spread, int slot,
    int N, int K, int gelu_mode) {
  __shared__ __attribute__((aligned(16))) f16 sA[128 * 32];
  __shared__ __attribute__((aligned(16))) f16 sB[128 * 32];
  int tid = threadIdx.x;
  int n0 = blockIdx.x * 128, m0 = blockIdx.y * 128;
  int lane = tid & 63, wv = tid >> 6;
  int wm = (wv & 1) * 64, wn = (wv >> 1) * 64;
  int lr = lane & 15, quad = lane >> 4;

  f32x4 acc[4][4];
#pragma unroll
  for (int i = 0; i < 4; ++i)
#pragma unroll
    for (int j = 0; j < 4; ++j) acc[i][j] = f32x4{0.f, 0.f, 0.f, 0.f};

  for (int k0 = 0; k0 < K; k0 += 32) {
#pragma unroll
    for (int it = 0; it < 2; ++it) {
      int c = it * 256 + tid;      // 512 chunks of 16B per tile
      int r = c >> 2, kc = c & 3;
      async_copy16(&sA[c * 8], A + (size_t)(m0 + r) * K + k0 + kc * 8);
      async_copy16(&sB[c * 8], B + (size_t)(n0 + r) * K + k0 + kc * 8);
    }
    __syncthreads();
    half8 af[4], bfv[4];
#pragma unroll
    for (int i = 0; i < 4; ++i)
      af[i] = *(const half8*)&sA[(wm + i * 16 + lr) * 32 + quad * 8];
#pragma unroll
    for (int j = 0; j < 4; ++j)
      bfv[j] = *(const half8*)&sB[(wn + j * 16 + lr) * 32 + quad * 8];
#pragma unroll
    for (int i = 0; i < 4; ++i)
#pragma unroll
      for (int j = 0; j < 4; ++j)
        acc[i][j] = __builtin_amdgcn_mfma_f32_16x16x32_f16(af[i], bfv[j],
                                                           acc[i][j], 0, 0, 0);
    __syncthreads();
  }

  // epilogue: C/D layout col=lane&15, row=quad*4+reg
  float lmax = 0.f;
#pragma unroll
  for (int i = 0; i < 4; ++i) {
    int r0 = m0 + wm + i * 16 + quad * 4;
#pragma unroll
    for (int j = 0; j < 4; ++j) {
      int col = n0 + wn + j * 16 + lr;
      float bv = bias[col];
#pragma unroll
      for (int reg = 0; reg < 4; ++reg) {
        size_t idx = (size_t)(r0 + reg) * N + col;
        float v = acc[i][j][reg] + bv;
        if (resid) v += resid[idx];
        if (gelu_mode) {
          v = gelu_exact(v);
          lmax = fmaxf(lmax, fabsf(v));
        }
        if (outf) outf[idx] = v;
        else outh[idx] = (f16)v;
      }
    }
  }
  if (gelu_mode) {
    float bm = block_reduce_max(lmax);
    if (tid == 0)
      atomicMax(spread_cell(spread, slot, blockIdx.x + gridDim.x * blockIdx.y),
                __float_as_uint(bm));
  }
}

// ---------------------------------------------------------------- attention
__global__ __launch_bounds__(256) void attn_k(f16* __restrict__ qkv,
                                              unsigned* spread, int slot) {
  __shared__ float sQ[64][65];
  __shared__ float sK[64][65];
  __shared__ float sV[64][65];
  int tid = threadIdx.x, lane = tid & 63, wv = tid >> 6;
  int blk = blockIdx.x;
  int h = blk % 12, bc = blk / 12;
  size_t base = (size_t)bc * 64 * 2304;
  int qo = h * 64, ko = 768 + h * 64, vo = 1536 + h * 64;

  for (int idx = tid; idx < 4096; idx += 256) {
    int t = idx >> 6, d = idx & 63;
    size_t r = base + (size_t)t * 2304;
    sQ[t][d] = (float)qkv[r + qo + d];
    sK[t][d] = (float)qkv[r + ko + d];
    sV[t][d] = (float)qkv[r + vo + d];
  }
  __syncthreads();

  float p[16];
#pragma unroll
  for (int it = 0; it < 16; ++it) {
    int t = wv + 4 * it;
    float a = 0.f;
    for (int k = 0; k < 64; ++k) a += sQ[t][k] * sK[lane][k];
    p[it] = a * 0.125f;
  }
#pragma unroll
  for (int it = 0; it < 16; ++it) {
    float v = p[it], m = v;
    for (int o = 32; o; o >>= 1) m = fmaxf(m, __shfl_xor(m, o));
    float e = expf(v - m);
    float den = e;
    for (int o = 32; o; o >>= 1) den += __shfl_xor(den, o);
    p[it] = e / den;
  }
  __syncthreads();
#pragma unroll
  for (int it = 0; it < 16; ++it) sQ[wv + 4 * it][lane] = p[it];
  __syncthreads();

  float lmax = 0.f;
  for (int idx = tid; idx < 4096; idx += 256) {
    int t = idx >> 6, d = idx & 63;
    float a = 0.f;
    for (int s2 = 0; s2 < 64; ++s2) a += sQ[t][s2] * sV[s2][d];
    qkv[base + (size_t)t * 2304 + qo + d] = (f16)a;
    lmax = fmaxf(lmax, fabsf(a));
  }
  lmax = block_reduce_max(lmax);
  if (tid == 0)
    atomicMax(spread_cell(spread, slot, blockIdx.x), __float_as_uint(lmax));
}

// ---------------------------------------------------------------- launch

extern "C" void kernel_launch(void* const* d_in, const int* in_sizes, int n_in,
                              void* d_out, int out_size, void* d_ws,
                              size_t ws_size, hipStream_t stream) {
  (void)in_sizes; (void)n_in; (void)out_size; (void)ws_size;
  const float* x      = (const float*)d_in[0];
  const float* ln1_g  = (const float*)d_in[1];
  const float* ln1_b  = (const float*)d_in[2];
  const float* qkv_w  = (const float*)d_in[3];
  const float* qkv_b  = (const float*)d_in[4];
  const float* proj_w = (const float*)d_in[5];
  const float* proj_b = (const float*)d_in[6];
  const float* ln2_g  = (const float*)d_in[7];
  const float* ln2_b  = (const float*)d_in[8];
  const float* fc1_w  = (const float*)d_in[9];
  const float* fc1_b  = (const float*)d_in[10];
  const float* fc2_w  = (const float*)d_in[11];
  const float* fc2_b  = (const float*)d_in[12];
  float* out = (float*)d_out;

  char* ws = (char*)d_ws;
  unsigned* spread = (unsigned*)ws;                  // 8 slots x 64 cells x 64B
  unsigned* finals = (unsigned*)(ws + 8 * 64 * SPREAD_STRIDE * 4);
  f16* qkv_wq  = (f16*)(ws + 33280);
  f16* proj_wq = qkv_wq + 1769472;
  f16* fc1_wq  = proj_wq + 589824;
  f16* fc2_wq  = fc1_wq + 2359296;
  f16* hbuf    = fc2_wq + 2359296;   // 25165824 f16: LN out / quantized acts
  f16* big     = hbuf + 25165824;    // qkv f16 [M,2304] then gelu f16 [M,3072]

  zero_spread_k<<<(8 * 64 * SPREAD_STRIDE + 255) / 256, 256, 0, stream>>>(spread);

  absmax_k<<<256, 256, 0, stream>>>(qkv_w, 1769472 / 4, spread, 1);
  absmax_k<<<256, 256, 0, stream>>>(proj_w, 589824 / 4, spread, 2);
  absmax_k<<<256, 256, 0, stream>>>(fc1_w, 2359296 / 4, spread, 3);
  absmax_k<<<256, 256, 0, stream>>>(fc2_w, 2359296 / 4, spread, 4);
  reduce_slots_k<<<1, 256, 0, stream>>>(spread, finals, 1, 4);
  quant_w_k<<<(1769472 + 255) / 256, 256, 0, stream>>>(qkv_w, 1769472, finals + 1, qkv_wq);
  quant_w_k<<<(589824 + 255) / 256, 256, 0, stream>>>(proj_w, 589824, finals + 2, proj_wq);
  quant_w_k<<<(2359296 + 255) / 256, 256, 0, stream>>>(fc1_w, 2359296, finals + 3, fc1_wq);
  quant_w_k<<<(2359296 + 255) / 256, 256, 0, stream>>>(fc2_w, 2359296, finals + 4, fc2_wq);

  // LN1 -> hbuf (f16), then in-place fq
  ln_k<<<32768, 256, 0, stream>>>(x, ln1_g, ln1_b, hbuf, spread, 0);
  reduce_slots_k<<<1, 64, 0, stream>>>(spread, finals, 0, 1);
  requant_k<<<NE_TOT / 8 / 256, 256, 0, stream>>>(hbuf, NE_TOT / 8, finals + 0);
  // qkv = h @ qkv_w^T + b -> big
  gemm_k<<<dim3(18, 256), 256, 0, stream>>>(hbuf, qkv_wq, qkv_b, nullptr,
                                            nullptr, big, nullptr, 0, 2304, 768, 0);
  // attention in place (o -> Q slice of big)
  attn_k<<<6144, 256, 0, stream>>>(big, spread, 5);
  reduce_slots_k<<<1, 64, 0, stream>>>(spread, finals, 5, 1);
  // fq(o) -> hbuf
  quant_strided_k<<<NE_TOT / 8 / 256, 256, 0, stream>>>(big, finals + 5, hbuf);
  // x2 = o_q @ proj_w^T + b + x -> out
  gemm_k<<<dim3(6, 256), 256, 0, stream>>>(hbuf, proj_wq, proj_b, x,
                                           out, nullptr, nullptr, 0, 768, 768, 0);
  // LN2 -> hbuf, fq
  ln_k<<<32768, 256, 0, stream>>>(out, ln2_g, ln2_b, hbuf, spread, 6);
  reduce_slots_k<<<1, 64, 0, stream>>>(spread, finals, 6, 1);
  requant_k<<<NE_TOT / 8 / 256, 256, 0, stream>>>(hbuf, NE_TOT / 8, finals + 6);
  // g = gelu(h @ fc1_w^T + b) -> big + absmax
  gemm_k<<<dim3(24, 256), 256, 0, stream>>>(hbuf, fc1_wq, fc1_b, nullptr,
                                            nullptr, big, spread, 7, 3072, 768, 1);
  reduce_slots_k<<<1, 64, 0, stream>>>(spread, finals, 7, 1);
  // fq(g) in place
  requant_k<<<100663296 / 8 / 256, 256, 0, stream>>>(big, 100663296 / 8, finals + 7);
  // out = g_q @ fc2_w^T + b + x2 (in-place residual)
  gemm_k<<<dim3(6, 256), 256, 0, stream>>>(big, fc2_wq, fc2_b, out,
                                           out, nullptr, nullptr, 0, 768, 3072, 0);
}

// Round 3
// 1278.350 us; speedup vs baseline: 3.8632x; 1.2447x over previous
//
#include <hip/hip_runtime.h>
#include <cmath>
#include <cstdint>

typedef _Float16 f16;
typedef _Float16 half8 __attribute__((ext_vector_type(8)));
typedef float f32x4 __attribute__((ext_vector_type(4)));
typedef int i32x4 __attribute__((ext_vector_type(4)));
typedef int8_t c8v __attribute__((ext_vector_type(8)));
typedef int8_t c4v __attribute__((ext_vector_type(4)));

#define M_TOTAL 32768     // B * C * T = 8 * 4096
#define D_MODEL 768
#define NE_TOT  25165824  // M_TOTAL * D_MODEL
#define SPREAD_STRIDE 16  // unsigneds between atomic cells (64 B: own cache line)

// ---------------------------------------------------------------- utilities

__device__ __forceinline__ void async_copy16(void* lds, const void* gmem) {
  __builtin_amdgcn_global_load_lds(
      (__attribute__((address_space(1))) void*)gmem,
      (__attribute__((address_space(3))) void*)lds, 16, 0, 0);
}

__device__ __forceinline__ float gelu_exact(float v) {
  return 0.5f * v * (1.0f + erff(v * 0.70710678118654752f));
}

__device__ __forceinline__ float slot_scale(const unsigned* slot) {
  return fmaxf(__uint_as_float(*slot), 1e-8f) / 127.0f;
}

__device__ __forceinline__ int8_t q8_val(float v, float s) {
  float q = fminf(fmaxf(rintf(v / s), -128.f), 127.f);
  return (int8_t)(int)q;
}

// 256-thread block max reduction (4 waves)
__device__ __forceinline__ float block_reduce_max(float m) {
  __shared__ float red_brm[4];
  for (int o = 32; o; o >>= 1) m = fmaxf(m, __shfl_down(m, o));
  int lane = threadIdx.x & 63, wv = threadIdx.x >> 6;
  if (lane == 0) red_brm[wv] = m;
  __syncthreads();
  return fmaxf(fmaxf(red_brm[0], red_brm[1]), fmaxf(red_brm[2], red_brm[3]));
}

__device__ __forceinline__ unsigned* spread_cell(unsigned* spread, int slot,
                                                 int cell) {
  return spread + slot * 64 * SPREAD_STRIDE + (cell & 63) * SPREAD_STRIDE;
}

// ---------------------------------------------------------------- small kernels

__global__ void zero_spread_k(unsigned* s) {
  int i = blockIdx.x * blockDim.x + threadIdx.x;
  if (i < 8 * 64 * SPREAD_STRIDE) s[i] = 0u;
}

__global__ void reduce_slots_k(const unsigned* __restrict__ spread,
                               unsigned* __restrict__ finals, int slot_lo,
                               int n_slots) {
  int wv = threadIdx.x >> 6, lane = threadIdx.x & 63;
  if (wv >= n_slots) return;
  int slot = slot_lo + wv;
  float m = __uint_as_float(spread[slot * 64 * SPREAD_STRIDE + lane * SPREAD_STRIDE]);
  for (int o = 32; o; o >>= 1) m = fmaxf(m, __shfl_down(m, o));
  if (lane == 0) finals[slot] = __float_as_uint(m);
}

__global__ __launch_bounds__(256) void absmax_k(const float* __restrict__ x,
                                                int n4, unsigned* spread,
                                                int slot) {
  int i = blockIdx.x * blockDim.x + threadIdx.x;
  int stride = gridDim.x * blockDim.x;
  float m = 0.f;
  const float4* x4 = (const float4*)x;
  for (; i < n4; i += stride) {
    float4 v = x4[i];
    m = fmaxf(m, fmaxf(fmaxf(fabsf(v.x), fabsf(v.y)),
                       fmaxf(fabsf(v.z), fabsf(v.w))));
  }
  m = block_reduce_max(m);
  if (threadIdx.x == 0)
    atomicMax(spread_cell(spread, slot, blockIdx.x), __float_as_uint(m));
}

// weights: f32 -> int8 (4/thread)
__global__ void quant_w8_k(const float* __restrict__ x, int n4,
                           const unsigned* __restrict__ slot,
                           int8_t* __restrict__ out) {
  int i = blockIdx.x * blockDim.x + threadIdx.x;
  if (i >= n4) return;
  float s = slot_scale(slot);
  float4 v = ((const float4*)x)[i];
  c4v q = {q8_val(v.x, s), q8_val(v.y, s), q8_val(v.z, s), q8_val(v.w, s)};
  ((c4v*)out)[i] = q;
}

// LayerNorm: write y (unquantized) as f16, accumulate global absmax of f32 y
__global__ __launch_bounds__(256) void ln_k(const float* __restrict__ x,
                                            const float* __restrict__ gw,
                                            const float* __restrict__ bw,
                                            f16* __restrict__ out,
                                            unsigned* spread, int slot) {
  int row = blockIdx.x, tid = threadIdx.x;
  const float* xr = x + (size_t)row * D_MODEL;
  float v0 = xr[tid], v1 = xr[tid + 256], v2 = xr[tid + 512];
  float s = v0 + v1 + v2;
  float ss = v0 * v0 + v1 * v1 + v2 * v2;
  for (int o = 32; o; o >>= 1) {
    s += __shfl_down(s, o);
    ss += __shfl_down(ss, o);
  }
  __shared__ float red[8];
  int lane = tid & 63, wv = tid >> 6;
  if (lane == 0) { red[wv] = s; red[4 + wv] = ss; }
  __syncthreads();
  float st = red[0] + red[1] + red[2] + red[3];
  float sst = red[4] + red[5] + red[6] + red[7];
  float mean = st * (1.f / 768.f);
  float var = sst * (1.f / 768.f) - mean * mean;
  float rstd = rsqrtf(var + 1e-5f);
  float y0 = (v0 - mean) * rstd * gw[tid] + bw[tid];
  float y1 = (v1 - mean) * rstd * gw[tid + 256] + bw[tid + 256];
  float y2 = (v2 - mean) * rstd * gw[tid + 512] + bw[tid + 512];
  f16* outr = out + (size_t)row * D_MODEL;
  outr[tid] = (f16)y0; outr[tid + 256] = (f16)y1; outr[tid + 512] = (f16)y2;
  float m = fmaxf(fabsf(y0), fmaxf(fabsf(y1), fabsf(y2)));
  __syncthreads();  // red[] done before helper's shared use
  m = block_reduce_max(m);
  if (tid == 0)
    atomicMax(spread_cell(spread, slot, blockIdx.x), __float_as_uint(m));
}

// dense f16 -> int8, 8 elems/thread
__global__ void quant8_k(const f16* __restrict__ src, int n8,
                         const unsigned* __restrict__ slot,
                         int8_t* __restrict__ out) {
  int i = blockIdx.x * blockDim.x + threadIdx.x;
  if (i >= n8) return;
  float s = slot_scale(slot);
  half8 v = ((const half8*)src)[i];
  c8v q;
#pragma unroll
  for (int j = 0; j < 8; ++j) q[j] = q8_val((float)v[j], s);
  ((c8v*)out)[i] = q;
}

// attention output: strided read of Q slice of qkv buffer -> dense int8
__global__ void quant_strided8_k(const f16* __restrict__ src,
                                 const unsigned* __restrict__ slot,
                                 int8_t* __restrict__ out) {
  int i = blockIdx.x * blockDim.x + threadIdx.x;  // 8-elem groups
  if (i >= NE_TOT / 8) return;
  int row = i / 96, c8 = i - row * 96;
  half8 v = *(const half8*)(src + (size_t)row * 2304 + c8 * 8);
  float s = slot_scale(slot);
  c8v q;
#pragma unroll
  for (int j = 0; j < 8; ++j) q[j] = q8_val((float)v[j], s);
  ((c8v*)out)[i] = q;
}

// ---------------------------------------------------------------- int8 GEMM
// C[m,n] = (sum_k qA[m,k]*qB[n,k]) * sA*sB + bias[n] (+resid) (+gelu).
// 128x128 tile, BK=64 (bytes), 4 waves of 64x64, mfma_i32_16x16x64_i8,
// global_load_lds width-16 staging. Exact integer dot products.
__global__ __launch_bounds__(256) void gemm_i8_k(
    const int8_t* __restrict__ A, const int8_t* __restrict__ B,
    const unsigned* __restrict__ slotA, const unsigned* __restrict__ slotB,
    const float* __restrict__ bias, const float* resid,
    float* outf, f16* outh, unsigned* spread, int slot,
    int N, int K, int gelu_mode) {
  __shared__ __attribute__((aligned(16))) int8_t sA[128 * 64];
  __shared__ __attribute__((aligned(16))) int8_t sB[128 * 64];
  int tid = threadIdx.x;
  int n0 = blockIdx.x * 128, m0 = blockIdx.y * 128;
  int lane = tid & 63, wv = tid >> 6;
  int wm = (wv & 1) * 64, wn = (wv >> 1) * 64;
  int lr = lane & 15, quad = lane >> 4;

  i32x4 acc[4][4];
#pragma unroll
  for (int i = 0; i < 4; ++i)
#pragma unroll
    for (int j = 0; j < 4; ++j) acc[i][j] = i32x4{0, 0, 0, 0};

  for (int k0 = 0; k0 < K; k0 += 64) {
#pragma unroll
    for (int it = 0; it < 2; ++it) {
      int c = it * 256 + tid;      // 512 chunks of 16B per tile
      int r = c >> 2, kc = c & 3;  // row, 16B column within the 64B row
      async_copy16(&sA[c * 16], A + (size_t)(m0 + r) * K + k0 + kc * 16);
      async_copy16(&sB[c * 16], B + (size_t)(n0 + r) * K + k0 + kc * 16);
    }
    __syncthreads();
    i32x4 af[4], bfv[4];
#pragma unroll
    for (int i = 0; i < 4; ++i)
      af[i] = *(const i32x4*)&sA[(wm + i * 16 + lr) * 64 + quad * 16];
#pragma unroll
    for (int j = 0; j < 4; ++j)
      bfv[j] = *(const i32x4*)&sB[(wn + j * 16 + lr) * 64 + quad * 16];
#pragma unroll
    for (int i = 0; i < 4; ++i)
#pragma unroll
      for (int j = 0; j < 4; ++j)
        acc[i][j] = __builtin_amdgcn_mfma_i32_16x16x64_i8(af[i], bfv[j],
                                                          acc[i][j], 0, 0, 0);
    __syncthreads();
  }

  float scale = slot_scale(slotA) * slot_scale(slotB);
  // epilogue: C/D layout col=lane&15, row=quad*4+reg
  float lmax = 0.f;
#pragma unroll
  for (int i = 0; i < 4; ++i) {
    int r0 = m0 + wm + i * 16 + quad * 4;
#pragma unroll
    for (int j = 0; j < 4; ++j) {
      int col = n0 + wn + j * 16 + lr;
      float bv = bias[col];
#pragma unroll
      for (int reg = 0; reg < 4; ++reg) {
        size_t idx = (size_t)(r0 + reg) * N + col;
        float v = (float)acc[i][j][reg] * scale + bv;
        if (resid) v += resid[idx];
        if (gelu_mode) {
          v = gelu_exact(v);
          lmax = fmaxf(lmax, fabsf(v));
        }
        if (outf) outf[idx] = v;
        else outh[idx] = (f16)v;
      }
    }
  }
  if (gelu_mode) {
    float bm = block_reduce_max(lmax);
    if (tid == 0)
      atomicMax(spread_cell(spread, slot, blockIdx.x + gridDim.x * blockIdx.y),
                __float_as_uint(bm));
  }
}

// ---------------------------------------------------------------- attention
__global__ __launch_bounds__(256) void attn_k(f16* __restrict__ qkv,
                                              unsigned* spread, int slot) {
  __shared__ float sQ[64][65];
  __shared__ float sK[64][65];
  __shared__ float sV[64][65];
  int tid = threadIdx.x, lane = tid & 63, wv = tid >> 6;
  int blk = blockIdx.x;
  int h = blk % 12, bc = blk / 12;
  size_t base = (size_t)bc * 64 * 2304;
  int qo = h * 64, ko = 768 + h * 64, vo = 1536 + h * 64;

  for (int idx = tid; idx < 4096; idx += 256) {
    int t = idx >> 6, d = idx & 63;
    size_t r = base + (size_t)t * 2304;
    sQ[t][d] = (float)qkv[r + qo + d];
    sK[t][d] = (float)qkv[r + ko + d];
    sV[t][d] = (float)qkv[r + vo + d];
  }
  __syncthreads();

  float p[16];
#pragma unroll
  for (int it = 0; it < 16; ++it) {
    int t = wv + 4 * it;
    float a = 0.f;
    for (int k = 0; k < 64; ++k) a += sQ[t][k] * sK[lane][k];
    p[it] = a * 0.125f;
  }
#pragma unroll
  for (int it = 0; it < 16; ++it) {
    float v = p[it], m = v;
    for (int o = 32; o; o >>= 1) m = fmaxf(m, __shfl_xor(m, o));
    float e = expf(v - m);
    float den = e;
    for (int o = 32; o; o >>= 1) den += __shfl_xor(den, o);
    p[it] = e / den;
  }
  __syncthreads();
#pragma unroll
  for (int it = 0; it < 16; ++it) sQ[wv + 4 * it][lane] = p[it];
  __syncthreads();

  float lmax = 0.f;
  for (int idx = tid; idx < 4096; idx += 256) {
    int t = idx >> 6, d = idx & 63;
    float a = 0.f;
    for (int s2 = 0; s2 < 64; ++s2) a += sQ[t][s2] * sV[s2][d];
    qkv[base + (size_t)t * 2304 + qo + d] = (f16)a;
    lmax = fmaxf(lmax, fabsf(a));
  }
  lmax = block_reduce_max(lmax);
  if (tid == 0)
    atomicMax(spread_cell(spread, slot, blockIdx.x), __float_as_uint(lmax));
}

// ---------------------------------------------------------------- launch

extern "C" void kernel_launch(void* const* d_in, const int* in_sizes, int n_in,
                              void* d_out, int out_size, void* d_ws,
                              size_t ws_size, hipStream_t stream) {
  (void)in_sizes; (void)n_in; (void)out_size; (void)ws_size;
  const float* x      = (const float*)d_in[0];
  const float* ln1_g  = (const float*)d_in[1];
  const float* ln1_b  = (const float*)d_in[2];
  const float* qkv_w  = (const float*)d_in[3];
  const float* qkv_b  = (const float*)d_in[4];
  const float* proj_w = (const float*)d_in[5];
  const float* proj_b = (const float*)d_in[6];
  const float* ln2_g  = (const float*)d_in[7];
  const float* ln2_b  = (const float*)d_in[8];
  const float* fc1_w  = (const float*)d_in[9];
  const float* fc1_b  = (const float*)d_in[10];
  const float* fc2_w  = (const float*)d_in[11];
  const float* fc2_b  = (const float*)d_in[12];
  float* out = (float*)d_out;

  char* ws = (char*)d_ws;
  unsigned* spread = (unsigned*)ws;                       // 8 x 64 cells x 64B
  unsigned* finals = (unsigned*)(ws + 8 * 64 * SPREAD_STRIDE * 4);
  int8_t* qkv_wq  = (int8_t*)(ws + 33280);                // int8 weights
  int8_t* proj_wq = qkv_wq + 1769472;
  int8_t* fc1_wq  = proj_wq + 589824;
  int8_t* fc2_wq  = fc1_wq + 2359296;
  // g_q region (96 MB) also hosts hbuf (f16, 48 MB) + a_i8 (24 MB): both are
  // dead by the time g_q is written (after fc1).
  int8_t* g_q  = fc2_wq + 2359296;
  f16*    hbuf = (f16*)g_q;                               // LN y (f16)
  int8_t* a_i8 = g_q + 50331648;                          // quantized acts
  f16*    big  = (f16*)(g_q + 100663296);                 // qkv / gelu f16
  // total ws use ~309 MB

  zero_spread_k<<<(8 * 64 * SPREAD_STRIDE + 255) / 256, 256, 0, stream>>>(spread);

  absmax_k<<<256, 256, 0, stream>>>(qkv_w, 1769472 / 4, spread, 1);
  absmax_k<<<256, 256, 0, stream>>>(proj_w, 589824 / 4, spread, 2);
  absmax_k<<<256, 256, 0, stream>>>(fc1_w, 2359296 / 4, spread, 3);
  absmax_k<<<256, 256, 0, stream>>>(fc2_w, 2359296 / 4, spread, 4);
  reduce_slots_k<<<1, 256, 0, stream>>>(spread, finals, 1, 4);
  quant_w8_k<<<(1769472 / 4 + 255) / 256, 256, 0, stream>>>(qkv_w, 1769472 / 4, finals + 1, qkv_wq);
  quant_w8_k<<<(589824 / 4 + 255) / 256, 256, 0, stream>>>(proj_w, 589824 / 4, finals + 2, proj_wq);
  quant_w8_k<<<(2359296 / 4 + 255) / 256, 256, 0, stream>>>(fc1_w, 2359296 / 4, finals + 3, fc1_wq);
  quant_w8_k<<<(2359296 / 4 + 255) / 256, 256, 0, stream>>>(fc2_w, 2359296 / 4, finals + 4, fc2_wq);

  // LN1 -> hbuf (f16) + absmax; quantize -> a_i8
  ln_k<<<32768, 256, 0, stream>>>(x, ln1_g, ln1_b, hbuf, spread, 0);
  reduce_slots_k<<<1, 64, 0, stream>>>(spread, finals, 0, 1);
  quant8_k<<<NE_TOT / 8 / 256, 256, 0, stream>>>(hbuf, NE_TOT / 8, finals + 0, a_i8);
  // qkv = dequant(a_q @ qkv_wq^T) + b -> big (f16)
  gemm_i8_k<<<dim3(18, 256), 256, 0, stream>>>(a_i8, qkv_wq, finals + 0, finals + 1,
                                               qkv_b, nullptr, nullptr, big,
                                               nullptr, 0, 2304, 768, 0);
  // attention in place (o -> Q slice of big)
  attn_k<<<6144, 256, 0, stream>>>(big, spread, 5);
  reduce_slots_k<<<1, 64, 0, stream>>>(spread, finals, 5, 1);
  // fq(o) -> a_i8
  quant_strided8_k<<<NE_TOT / 8 / 256, 256, 0, stream>>>(big, finals + 5, a_i8);
  // x2 = o_q @ proj_wq^T + b + x -> out
  gemm_i8_k<<<dim3(6, 256), 256, 0, stream>>>(a_i8, proj_wq, finals + 5, finals + 2,
                                              proj_b, x, out, nullptr,
                                              nullptr, 0, 768, 768, 0);
  // LN2 -> hbuf + absmax; quantize -> a_i8
  ln_k<<<32768, 256, 0, stream>>>(out, ln2_g, ln2_b, hbuf, spread, 6);
  reduce_slots_k<<<1, 64, 0, stream>>>(spread, finals, 6, 1);
  quant8_k<<<NE_TOT / 8 / 256, 256, 0, stream>>>(hbuf, NE_TOT / 8, finals + 6, a_i8);
  // g = gelu(h_q @ fc1_wq^T + b) -> big (f16) + absmax
  gemm_i8_k<<<dim3(24, 256), 256, 0, stream>>>(a_i8, fc1_wq, finals + 6, finals + 3,
                                               fc1_b, nullptr, nullptr, big,
                                               spread, 7, 3072, 768, 1);
  reduce_slots_k<<<1, 64, 0, stream>>>(spread, finals, 7, 1);
  // fq(g) -> g_q (int8; overwrites dead hbuf/a_i8)
  quant8_k<<<100663296 / 8 / 256, 256, 0, stream>>>(big, 100663296 / 8, finals + 7, g_q);
  // out = g_q @ fc2_wq^T + b + x2 (in-place residual)
  gemm_i8_k<<<dim3(6, 256), 256, 0, stream>>>(g_q, fc2_wq, finals + 7, finals + 4,
                                              fc2_b, out, out, nullptr,
                                              nullptr, 0, 768, 3072, 0);
}

// Round 4
// 1042.856 us; speedup vs baseline: 4.7355x; 1.2258x over previous
//
#include <hip/hip_runtime.h>
#include <cmath>
#include <cstdint>

typedef _Float16 f16;
typedef _Float16 half8 __attribute__((ext_vector_type(8)));
typedef float f32x4 __attribute__((ext_vector_type(4)));
typedef int i32x4 __attribute__((ext_vector_type(4)));
typedef int8_t c8v __attribute__((ext_vector_type(8)));
typedef int8_t c4v __attribute__((ext_vector_type(4)));

#define M_TOTAL 32768     // B * C * T = 8 * 4096
#define D_MODEL 768
#define NE_TOT  25165824  // M_TOTAL * D_MODEL
#define SPREAD_STRIDE 16  // unsigneds between atomic cells (64 B: own cache line)

// ---------------------------------------------------------------- utilities

__device__ __forceinline__ void async_copy16(void* lds, const void* gmem) {
  __builtin_amdgcn_global_load_lds(
      (__attribute__((address_space(1))) void*)gmem,
      (__attribute__((address_space(3))) void*)lds, 16, 0, 0);
}

__device__ __forceinline__ float gelu_exact(float v) {
  return 0.5f * v * (1.0f + erff(v * 0.70710678118654752f));
}

__device__ __forceinline__ float slot_scale(const unsigned* slot) {
  return fmaxf(__uint_as_float(*slot), 1e-8f) / 127.0f;
}

__device__ __forceinline__ int8_t q8_val(float v, float s) {
  float q = fminf(fmaxf(rintf(v / s), -128.f), 127.f);
  return (int8_t)(int)q;
}

// 256-thread block max reduction (4 waves)
__device__ __forceinline__ float block_reduce_max(float m) {
  __shared__ float red_brm[4];
  for (int o = 32; o; o >>= 1) m = fmaxf(m, __shfl_down(m, o));
  int lane = threadIdx.x & 63, wv = threadIdx.x >> 6;
  if (lane == 0) red_brm[wv] = m;
  __syncthreads();
  return fmaxf(fmaxf(red_brm[0], red_brm[1]), fmaxf(red_brm[2], red_brm[3]));
}

__device__ __forceinline__ unsigned* spread_cell(unsigned* spread, int slot,
                                                 int cell) {
  return spread + slot * 64 * SPREAD_STRIDE + (cell & 63) * SPREAD_STRIDE;
}

// ---------------------------------------------------------------- small kernels

__global__ void zero_spread_k(unsigned* s) {
  int i = blockIdx.x * blockDim.x + threadIdx.x;
  if (i < 8 * 64 * SPREAD_STRIDE) s[i] = 0u;
}

__global__ void reduce_slots_k(const unsigned* __restrict__ spread,
                               unsigned* __restrict__ finals, int slot_lo,
                               int n_slots) {
  int wv = threadIdx.x >> 6, lane = threadIdx.x & 63;
  if (wv >= n_slots) return;
  int slot = slot_lo + wv;
  float m = __uint_as_float(spread[slot * 64 * SPREAD_STRIDE + lane * SPREAD_STRIDE]);
  for (int o = 32; o; o >>= 1) m = fmaxf(m, __shfl_down(m, o));
  if (lane == 0) finals[slot] = __float_as_uint(m);
}

__global__ __launch_bounds__(256) void absmax_k(const float* __restrict__ x,
                                                int n4, unsigned* spread,
                                                int slot) {
  int i = blockIdx.x * blockDim.x + threadIdx.x;
  int stride = gridDim.x * blockDim.x;
  float m = 0.f;
  const float4* x4 = (const float4*)x;
  for (; i < n4; i += stride) {
    float4 v = x4[i];
    m = fmaxf(m, fmaxf(fmaxf(fabsf(v.x), fabsf(v.y)),
                       fmaxf(fabsf(v.z), fabsf(v.w))));
  }
  m = block_reduce_max(m);
  if (threadIdx.x == 0)
    atomicMax(spread_cell(spread, slot, blockIdx.x), __float_as_uint(m));
}

// weights: f32 -> int8 (4/thread)
__global__ void quant_w8_k(const float* __restrict__ x, int n4,
                           const unsigned* __restrict__ slot,
                           int8_t* __restrict__ out) {
  int i = blockIdx.x * blockDim.x + threadIdx.x;
  if (i >= n4) return;
  float s = slot_scale(slot);
  float4 v = ((const float4*)x)[i];
  c4v q = {q8_val(v.x, s), q8_val(v.y, s), q8_val(v.z, s), q8_val(v.w, s)};
  ((c4v*)out)[i] = q;
}

// LayerNorm: write y (unquantized) as f16, accumulate global absmax of f32 y
__global__ __launch_bounds__(256) void ln_k(const float* __restrict__ x,
                                            const float* __restrict__ gw,
                                            const float* __restrict__ bw,
                                            f16* __restrict__ out,
                                            unsigned* spread, int slot) {
  int row = blockIdx.x, tid = threadIdx.x;
  const float* xr = x + (size_t)row * D_MODEL;
  float v0 = xr[tid], v1 = xr[tid + 256], v2 = xr[tid + 512];
  float s = v0 + v1 + v2;
  float ss = v0 * v0 + v1 * v1 + v2 * v2;
  for (int o = 32; o; o >>= 1) {
    s += __shfl_down(s, o);
    ss += __shfl_down(ss, o);
  }
  __shared__ float red[8];
  int lane = tid & 63, wv = tid >> 6;
  if (lane == 0) { red[wv] = s; red[4 + wv] = ss; }
  __syncthreads();
  float st = red[0] + red[1] + red[2] + red[3];
  float sst = red[4] + red[5] + red[6] + red[7];
  float mean = st * (1.f / 768.f);
  float var = sst * (1.f / 768.f) - mean * mean;
  float rstd = rsqrtf(var + 1e-5f);
  float y0 = (v0 - mean) * rstd * gw[tid] + bw[tid];
  float y1 = (v1 - mean) * rstd * gw[tid + 256] + bw[tid + 256];
  float y2 = (v2 - mean) * rstd * gw[tid + 512] + bw[tid + 512];
  f16* outr = out + (size_t)row * D_MODEL;
  outr[tid] = (f16)y0; outr[tid + 256] = (f16)y1; outr[tid + 512] = (f16)y2;
  float m = fmaxf(fabsf(y0), fmaxf(fabsf(y1), fabsf(y2)));
  __syncthreads();  // red[] done before helper's shared use
  m = block_reduce_max(m);
  if (tid == 0)
    atomicMax(spread_cell(spread, slot, blockIdx.x), __float_as_uint(m));
}

// dense f16 -> int8, 8 elems/thread
__global__ void quant8_k(const f16* __restrict__ src, int n8,
                         const unsigned* __restrict__ slot,
                         int8_t* __restrict__ out) {
  int i = blockIdx.x * blockDim.x + threadIdx.x;
  if (i >= n8) return;
  float s = slot_scale(slot);
  half8 v = ((const half8*)src)[i];
  c8v q;
#pragma unroll
  for (int j = 0; j < 8; ++j) q[j] = q8_val((float)v[j], s);
  ((c8v*)out)[i] = q;
}

// attention output: strided read of Q slice of qkv buffer -> dense int8
__global__ void quant_strided8_k(const f16* __restrict__ src,
                                 const unsigned* __restrict__ slot,
                                 int8_t* __restrict__ out) {
  int i = blockIdx.x * blockDim.x + threadIdx.x;  // 8-elem groups
  if (i >= NE_TOT / 8) return;
  int row = i / 96, c8 = i - row * 96;
  half8 v = *(const half8*)(src + (size_t)row * 2304 + c8 * 8);
  float s = slot_scale(slot);
  c8v q;
#pragma unroll
  for (int j = 0; j < 8; ++j) q[j] = q8_val((float)v[j], s);
  ((c8v*)out)[i] = q;
}

// ---------------------------------------------------------------- int8 GEMM
// C[m,n] = (sum_k qA[m,k]*qB[n,k]) * sA*sB + bias[n] (+resid) (+gelu).
// 128x128 tile, BK=64 (bytes), 4 waves of 64x64, mfma_i32_16x16x64_i8,
// global_load_lds width-16 staging. Exact integer dot products.
__global__ __launch_bounds__(256) void gemm_i8_k(
    const int8_t* __restrict__ A, const int8_t* __restrict__ B,
    const unsigned* __restrict__ slotA, const unsigned* __restrict__ slotB,
    const float* __restrict__ bias, const float* resid,
    float* outf, f16* outh, unsigned* spread, int slot,
    int N, int K, int gelu_mode) {
  __shared__ __attribute__((aligned(16))) int8_t sA[128 * 64];
  __shared__ __attribute__((aligned(16))) int8_t sB[128 * 64];
  int tid = threadIdx.x;
  int n0 = blockIdx.x * 128, m0 = blockIdx.y * 128;
  int lane = tid & 63, wv = tid >> 6;
  int wm = (wv & 1) * 64, wn = (wv >> 1) * 64;
  int lr = lane & 15, quad = lane >> 4;

  i32x4 acc[4][4];
#pragma unroll
  for (int i = 0; i < 4; ++i)
#pragma unroll
    for (int j = 0; j < 4; ++j) acc[i][j] = i32x4{0, 0, 0, 0};

  for (int k0 = 0; k0 < K; k0 += 64) {
#pragma unroll
    for (int it = 0; it < 2; ++it) {
      int c = it * 256 + tid;      // 512 chunks of 16B per tile
      int r = c >> 2, kc = c & 3;  // row, 16B column within the 64B row
      async_copy16(&sA[c * 16], A + (size_t)(m0 + r) * K + k0 + kc * 16);
      async_copy16(&sB[c * 16], B + (size_t)(n0 + r) * K + k0 + kc * 16);
    }
    __syncthreads();
    i32x4 af[4], bfv[4];
#pragma unroll
    for (int i = 0; i < 4; ++i)
      af[i] = *(const i32x4*)&sA[(wm + i * 16 + lr) * 64 + quad * 16];
#pragma unroll
    for (int j = 0; j < 4; ++j)
      bfv[j] = *(const i32x4*)&sB[(wn + j * 16 + lr) * 64 + quad * 16];
#pragma unroll
    for (int i = 0; i < 4; ++i)
#pragma unroll
      for (int j = 0; j < 4; ++j)
        acc[i][j] = __builtin_amdgcn_mfma_i32_16x16x64_i8(af[i], bfv[j],
                                                          acc[i][j], 0, 0, 0);
    __syncthreads();
  }

  float scale = slot_scale(slotA) * slot_scale(slotB);
  // epilogue: C/D layout col=lane&15, row=quad*4+reg
  float lmax = 0.f;
#pragma unroll
  for (int i = 0; i < 4; ++i) {
    int r0 = m0 + wm + i * 16 + quad * 4;
#pragma unroll
    for (int j = 0; j < 4; ++j) {
      int col = n0 + wn + j * 16 + lr;
      float bv = bias[col];
#pragma unroll
      for (int reg = 0; reg < 4; ++reg) {
        size_t idx = (size_t)(r0 + reg) * N + col;
        float v = (float)acc[i][j][reg] * scale + bv;
        if (resid) v += resid[idx];
        if (gelu_mode) {
          v = gelu_exact(v);
          lmax = fmaxf(lmax, fabsf(v));
        }
        if (outf) outf[idx] = v;
        else outh[idx] = (f16)v;
      }
    }
  }
  if (gelu_mode) {
    float bm = block_reduce_max(lmax);
    if (tid == 0)
      atomicMax(spread_cell(spread, slot, blockIdx.x + gridDim.x * blockIdx.y),
                __float_as_uint(bm));
  }
}

// ---------------------------------------------------------------- attention
// one block per (b,c,head). MFMA path: S = Q K^T (16x16x32 f16, wave = 16-row
// strip), register softmax (row lives on 16 lanes x 4 tiles), P -> LDS
// (C-layout -> A-layout transform), O = P V. O written over the Q slice.
__global__ __launch_bounds__(256) void attn_k(f16* __restrict__ qkv,
                                              unsigned* spread, int slot) {
  // stride 72 f16: rows stay 16B-aligned; ds_read_b128 fragments hit all 8
  // bank-phases evenly ((lr*9+quad)%8 uniform)
  __shared__ __attribute__((aligned(16))) f16 sQ[64 * 72];
  __shared__ __attribute__((aligned(16))) f16 sK[64 * 72];
  __shared__ __attribute__((aligned(16))) f16 sV[64 * 72];
  __shared__ __attribute__((aligned(16))) f16 sP[64 * 72];
  int tid = threadIdx.x, lane = tid & 63, wv = tid >> 6;
  int lr = lane & 15, quad = lane >> 4;
  int h = blockIdx.x % 12, bc = blockIdx.x / 12;
  size_t base = (size_t)bc * 64 * 2304;
  int qo = h * 64, ko = qo + 768, vo = qo + 1536;

#pragma unroll
  for (int p = 0; p < 2; ++p) {
    int idx = p * 256 + tid;     // 512 chunks of 8 f16
    int t = idx >> 3, d8 = idx & 7;
    size_t g = base + (size_t)t * 2304 + d8 * 8;
    *(half8*)&sQ[t * 72 + d8 * 8] = *(const half8*)(qkv + g + qo);
    *(half8*)&sK[t * 72 + d8 * 8] = *(const half8*)(qkv + g + ko);
    *(half8*)&sV[t * 72 + d8 * 8] = *(const half8*)(qkv + g + vo);
  }
  __syncthreads();

  // S = Q K^T: wave wv owns rows wv*16 .. wv*16+15; 4 col tiles j
  f32x4 acc[4];
#pragma unroll
  for (int j = 0; j < 4; ++j) acc[j] = f32x4{0.f, 0.f, 0.f, 0.f};
#pragma unroll
  for (int ks = 0; ks < 2; ++ks) {
    half8 aq = *(const half8*)&sQ[(wv * 16 + lr) * 72 + ks * 32 + quad * 8];
#pragma unroll
    for (int j = 0; j < 4; ++j) {
      half8 bk = *(const half8*)&sK[(j * 16 + lr) * 72 + ks * 32 + quad * 8];
      acc[j] = __builtin_amdgcn_mfma_f32_16x16x32_f16(aq, bk, acc[j], 0, 0, 0);
    }
  }

  // softmax: row (quad,reg) spans 16 lanes (lr) x 4 tiles (j)
  float pr[4][4];  // [j][reg]
#pragma unroll
  for (int reg = 0; reg < 4; ++reg) {
    float v0 = acc[0][reg] * 0.125f, v1 = acc[1][reg] * 0.125f;
    float v2 = acc[2][reg] * 0.125f, v3 = acc[3][reg] * 0.125f;
    float mx = fmaxf(fmaxf(v0, v1), fmaxf(v2, v3));
    for (int o = 8; o; o >>= 1) mx = fmaxf(mx, __shfl_xor(mx, o));
    float e0 = __expf(v0 - mx), e1 = __expf(v1 - mx);
    float e2 = __expf(v2 - mx), e3 = __expf(v3 - mx);
    float sum = e0 + e1 + e2 + e3;
    for (int o = 8; o; o >>= 1) sum += __shfl_xor(sum, o);
    float inv = 1.f / sum;
    pr[0][reg] = e0 * inv; pr[1][reg] = e1 * inv;
    pr[2][reg] = e2 * inv; pr[3][reg] = e3 * inv;
  }
  // P: C-layout -> natural row-major in LDS (scalar b16, ~2-way conflicts)
#pragma unroll
  for (int j = 0; j < 4; ++j)
#pragma unroll
    for (int reg = 0; reg < 4; ++reg)
      sP[(wv * 16 + quad * 4 + reg) * 72 + j * 16 + lr] = (f16)pr[j][reg];
  __syncthreads();

  // O = P V: A from sP rows (vector), B = V[s][d] column reads (scalar u16)
  f32x4 oacc[4];
#pragma unroll
  for (int j = 0; j < 4; ++j) oacc[j] = f32x4{0.f, 0.f, 0.f, 0.f};
#pragma unroll
  for (int ks = 0; ks < 2; ++ks) {
    half8 ap = *(const half8*)&sP[(wv * 16 + lr) * 72 + ks * 32 + quad * 8];
#pragma unroll
    for (int j = 0; j < 4; ++j) {
      half8 bv;
#pragma unroll
      for (int jj = 0; jj < 8; ++jj)
        bv[jj] = sV[(ks * 32 + quad * 8 + jj) * 72 + j * 16 + lr];
      oacc[j] = __builtin_amdgcn_mfma_f32_16x16x32_f16(ap, bv, oacc[j], 0, 0, 0);
    }
  }

  float lmax = 0.f;
#pragma unroll
  for (int j = 0; j < 4; ++j)
#pragma unroll
    for (int reg = 0; reg < 4; ++reg) {
      int m = wv * 16 + quad * 4 + reg;
      float v = oacc[j][reg];
      qkv[base + (size_t)m * 2304 + qo + j * 16 + lr] = (f16)v;
      lmax = fmaxf(lmax, fabsf(v));
    }
  lmax = block_reduce_max(lmax);
  if (tid == 0)
    atomicMax(spread_cell(spread, slot, blockIdx.x), __float_as_uint(lmax));
}

// ---------------------------------------------------------------- launch

extern "C" void kernel_launch(void* const* d_in, const int* in_sizes, int n_in,
                              void* d_out, int out_size, void* d_ws,
                              size_t ws_size, hipStream_t stream) {
  (void)in_sizes; (void)n_in; (void)out_size; (void)ws_size;
  const float* x      = (const float*)d_in[0];
  const float* ln1_g  = (const float*)d_in[1];
  const float* ln1_b  = (const float*)d_in[2];
  const float* qkv_w  = (const float*)d_in[3];
  const float* qkv_b  = (const float*)d_in[4];
  const float* proj_w = (const float*)d_in[5];
  const float* proj_b = (const float*)d_in[6];
  const float* ln2_g  = (const float*)d_in[7];
  const float* ln2_b  = (const float*)d_in[8];
  const float* fc1_w  = (const float*)d_in[9];
  const float* fc1_b  = (const float*)d_in[10];
  const float* fc2_w  = (const float*)d_in[11];
  const float* fc2_b  = (const float*)d_in[12];
  float* out = (float*)d_out;

  char* ws = (char*)d_ws;
  unsigned* spread = (unsigned*)ws;                       // 8 x 64 cells x 64B
  unsigned* finals = (unsigned*)(ws + 8 * 64 * SPREAD_STRIDE * 4);
  int8_t* qkv_wq  = (int8_t*)(ws + 33280);                // int8 weights
  int8_t* proj_wq = qkv_wq + 1769472;
  int8_t* fc1_wq  = proj_wq + 589824;
  int8_t* fc2_wq  = fc1_wq + 2359296;
  // g_q region (96 MB) also hosts hbuf (f16, 48 MB) + a_i8 (24 MB): both are
  // dead by the time g_q is written (after fc1).
  int8_t* g_q  = fc2_wq + 2359296;
  f16*    hbuf = (f16*)g_q;                               // LN y (f16)
  int8_t* a_i8 = g_q + 50331648;                          // quantized acts
  f16*    big  = (f16*)(g_q + 100663296);                 // qkv / gelu f16
  // total ws use ~309 MB

  zero_spread_k<<<(8 * 64 * SPREAD_STRIDE + 255) / 256, 256, 0, stream>>>(spread);

  absmax_k<<<256, 256, 0, stream>>>(qkv_w, 1769472 / 4, spread, 1);
  absmax_k<<<256, 256, 0, stream>>>(proj_w, 589824 / 4, spread, 2);
  absmax_k<<<256, 256, 0, stream>>>(fc1_w, 2359296 / 4, spread, 3);
  absmax_k<<<256, 256, 0, stream>>>(fc2_w, 2359296 / 4, spread, 4);
  reduce_slots_k<<<1, 256, 0, stream>>>(spread, finals, 1, 4);
  quant_w8_k<<<(1769472 / 4 + 255) / 256, 256, 0, stream>>>(qkv_w, 1769472 / 4, finals + 1, qkv_wq);
  quant_w8_k<<<(589824 / 4 + 255) / 256, 256, 0, stream>>>(proj_w, 589824 / 4, finals + 2, proj_wq);
  quant_w8_k<<<(2359296 / 4 + 255) / 256, 256, 0, stream>>>(fc1_w, 2359296 / 4, finals + 3, fc1_wq);
  quant_w8_k<<<(2359296 / 4 + 255) / 256, 256, 0, stream>>>(fc2_w, 2359296 / 4, finals + 4, fc2_wq);

  // LN1 -> hbuf (f16) + absmax; quantize -> a_i8
  ln_k<<<32768, 256, 0, stream>>>(x, ln1_g, ln1_b, hbuf, spread, 0);
  reduce_slots_k<<<1, 64, 0, stream>>>(spread, finals, 0, 1);
  quant8_k<<<NE_TOT / 8 / 256, 256, 0, stream>>>(hbuf, NE_TOT / 8, finals + 0, a_i8);
  // qkv = dequant(a_q @ qkv_wq^T) + b -> big (f16)
  gemm_i8_k<<<dim3(18, 256), 256, 0, stream>>>(a_i8, qkv_wq, finals + 0, finals + 1,
                                               qkv_b, nullptr, nullptr, big,
                                               nullptr, 0, 2304, 768, 0);
  // attention in place (o -> Q slice of big)
  attn_k<<<6144, 256, 0, stream>>>(big, spread, 5);
  reduce_slots_k<<<1, 64, 0, stream>>>(spread, finals, 5, 1);
  // fq(o) -> a_i8
  quant_strided8_k<<<NE_TOT / 8 / 256, 256, 0, stream>>>(big, finals + 5, a_i8);
  // x2 = o_q @ proj_wq^T + b + x -> out
  gemm_i8_k<<<dim3(6, 256), 256, 0, stream>>>(a_i8, proj_wq, finals + 5, finals + 2,
                                              proj_b, x, out, nullptr,
                                              nullptr, 0, 768, 768, 0);
  // LN2 -> hbuf + absmax; quantize -> a_i8
  ln_k<<<32768, 256, 0, stream>>>(out, ln2_g, ln2_b, hbuf, spread, 6);
  reduce_slots_k<<<1, 64, 0, stream>>>(spread, finals, 6, 1);
  quant8_k<<<NE_TOT / 8 / 256, 256, 0, stream>>>(hbuf, NE_TOT / 8, finals + 6, a_i8);
  // g = gelu(h_q @ fc1_wq^T + b) -> big (f16) + absmax
  gemm_i8_k<<<dim3(24, 256), 256, 0, stream>>>(a_i8, fc1_wq, finals + 6, finals + 3,
                                               fc1_b, nullptr, nullptr, big,
                                               spread, 7, 3072, 768, 1);
  reduce_slots_k<<<1, 64, 0, stream>>>(spread, finals, 7, 1);
  // fq(g) -> g_q (int8; overwrites dead hbuf/a_i8)
  quant8_k<<<100663296 / 8 / 256, 256, 0, stream>>>(big, 100663296 / 8, finals + 7, g_q);
  // out = g_q @ fc2_wq^T + b + x2 (in-place residual)
  gemm_i8_k<<<dim3(6, 256), 256, 0, stream>>>(g_q, fc2_wq, finals + 7, finals + 4,
                                              fc2_b, out, out, nullptr,
                                              nullptr, 0, 768, 3072, 0);
}

// Round 5
// 1016.518 us; speedup vs baseline: 4.8582x; 1.0259x over previous
//
#include <hip/hip_runtime.h>
#include <cmath>
#include <cstdint>

typedef _Float16 f16;
typedef _Float16 half8 __attribute__((ext_vector_type(8)));
typedef float f32x4 __attribute__((ext_vector_type(4)));
typedef int i32x4 __attribute__((ext_vector_type(4)));
typedef int8_t c8v __attribute__((ext_vector_type(8)));
typedef int8_t c4v __attribute__((ext_vector_type(4)));

#define M_TOTAL 32768     // B * C * T = 8 * 4096
#define D_MODEL 768
#define NE_TOT  25165824  // M_TOTAL * D_MODEL
#define SPREAD_STRIDE 16  // unsigneds between atomic cells (64 B: own cache line)

// ---------------------------------------------------------------- utilities

__device__ __forceinline__ void async_copy16(void* lds, const void* gmem) {
  __builtin_amdgcn_global_load_lds(
      (__attribute__((address_space(1))) void*)gmem,
      (__attribute__((address_space(3))) void*)lds, 16, 0, 0);
}

// gelu with A&S 7.1.26 erf approx: |erf err| <= 1.5e-7 (far below the f16
// rounding of the stored result). ~16 VALU ops vs ~35 for libm erff.
__device__ __forceinline__ float gelu_fast(float v) {
  float x = v * 0.70710678118654752f;
  float ax = fabsf(x);
  float t = __builtin_amdgcn_rcpf(fmaf(0.3275911f, ax, 1.0f));
  float y = t * (0.254829592f +
            t * (-0.284496736f +
            t * (1.421413741f +
            t * (-1.453152027f + t * 1.061405429f))));
  float e = __expf(-x * x);
  float erf_ax = fmaf(-y, e, 1.0f);
  float erf_x = copysignf(erf_ax, x);
  return 0.5f * v * (1.0f + erf_x);
}

__device__ __forceinline__ float slot_scale(const unsigned* slot) {
  return fmaxf(__uint_as_float(*slot), 1e-8f) / 127.0f;
}

__device__ __forceinline__ int8_t q8_val(float v, float s) {
  float q = fminf(fmaxf(rintf(v / s), -128.f), 127.f);
  return (int8_t)(int)q;
}

// 256-thread block max reduction (4 waves)
__device__ __forceinline__ float block_reduce_max(float m) {
  __shared__ float red_brm[4];
  for (int o = 32; o; o >>= 1) m = fmaxf(m, __shfl_down(m, o));
  int lane = threadIdx.x & 63, wv = threadIdx.x >> 6;
  if (lane == 0) red_brm[wv] = m;
  __syncthreads();
  return fmaxf(fmaxf(red_brm[0], red_brm[1]), fmaxf(red_brm[2], red_brm[3]));
}

__device__ __forceinline__ unsigned* spread_cell(unsigned* spread, int slot,
                                                 int cell) {
  return spread + slot * 64 * SPREAD_STRIDE + (cell & 63) * SPREAD_STRIDE;
}

// ---------------------------------------------------------------- small kernels

__global__ void zero_spread_k(unsigned* s) {
  int i = blockIdx.x * blockDim.x + threadIdx.x;
  if (i < 8 * 64 * SPREAD_STRIDE) s[i] = 0u;
}

__global__ void reduce_slots_k(const unsigned* __restrict__ spread,
                               unsigned* __restrict__ finals, int slot_lo,
                               int n_slots) {
  int wv = threadIdx.x >> 6, lane = threadIdx.x & 63;
  if (wv >= n_slots) return;
  int slot = slot_lo + wv;
  float m = __uint_as_float(spread[slot * 64 * SPREAD_STRIDE + lane * SPREAD_STRIDE]);
  for (int o = 32; o; o >>= 1) m = fmaxf(m, __shfl_down(m, o));
  if (lane == 0) finals[slot] = __float_as_uint(m);
}

__global__ __launch_bounds__(256) void absmax_k(const float* __restrict__ x,
                                                int n4, unsigned* spread,
                                                int slot) {
  int i = blockIdx.x * blockDim.x + threadIdx.x;
  int stride = gridDim.x * blockDim.x;
  float m = 0.f;
  const float4* x4 = (const float4*)x;
  for (; i < n4; i += stride) {
    float4 v = x4[i];
    m = fmaxf(m, fmaxf(fmaxf(fabsf(v.x), fabsf(v.y)),
                       fmaxf(fabsf(v.z), fabsf(v.w))));
  }
  m = block_reduce_max(m);
  if (threadIdx.x == 0)
    atomicMax(spread_cell(spread, slot, blockIdx.x), __float_as_uint(m));
}

// weights: f32 -> int8 (4/thread)
__global__ void quant_w8_k(const float* __restrict__ x, int n4,
                           const unsigned* __restrict__ slot,
                           int8_t* __restrict__ out) {
  int i = blockIdx.x * blockDim.x + threadIdx.x;
  if (i >= n4) return;
  float s = slot_scale(slot);
  float4 v = ((const float4*)x)[i];
  c4v q = {q8_val(v.x, s), q8_val(v.y, s), q8_val(v.z, s), q8_val(v.w, s)};
  ((c4v*)out)[i] = q;
}

// LayerNorm: write y (unquantized) as f16, accumulate global absmax of f32 y
__global__ __launch_bounds__(256) void ln_k(const float* __restrict__ x,
                                            const float* __restrict__ gw,
                                            const float* __restrict__ bw,
                                            f16* __restrict__ out,
                                            unsigned* spread, int slot) {
  int row = blockIdx.x, tid = threadIdx.x;
  const float* xr = x + (size_t)row * D_MODEL;
  float v0 = xr[tid], v1 = xr[tid + 256], v2 = xr[tid + 512];
  float s = v0 + v1 + v2;
  float ss = v0 * v0 + v1 * v1 + v2 * v2;
  for (int o = 32; o; o >>= 1) {
    s += __shfl_down(s, o);
    ss += __shfl_down(ss, o);
  }
  __shared__ float red[8];
  int lane = tid & 63, wv = tid >> 6;
  if (lane == 0) { red[wv] = s; red[4 + wv] = ss; }
  __syncthreads();
  float st = red[0] + red[1] + red[2] + red[3];
  float sst = red[4] + red[5] + red[6] + red[7];
  float mean = st * (1.f / 768.f);
  float var = sst * (1.f / 768.f) - mean * mean;
  float rstd = rsqrtf(var + 1e-5f);
  float y0 = (v0 - mean) * rstd * gw[tid] + bw[tid];
  float y1 = (v1 - mean) * rstd * gw[tid + 256] + bw[tid + 256];
  float y2 = (v2 - mean) * rstd * gw[tid + 512] + bw[tid + 512];
  f16* outr = out + (size_t)row * D_MODEL;
  outr[tid] = (f16)y0; outr[tid + 256] = (f16)y1; outr[tid + 512] = (f16)y2;
  float m = fmaxf(fabsf(y0), fmaxf(fabsf(y1), fabsf(y2)));
  __syncthreads();  // red[] done before helper's shared use
  m = block_reduce_max(m);
  if (tid == 0)
    atomicMax(spread_cell(spread, slot, blockIdx.x), __float_as_uint(m));
}

// dense f16 -> int8, 8 elems/thread
__global__ void quant8_k(const f16* __restrict__ src, int n8,
                         const unsigned* __restrict__ slot,
                         int8_t* __restrict__ out) {
  int i = blockIdx.x * blockDim.x + threadIdx.x;
  if (i >= n8) return;
  float s = slot_scale(slot);
  half8 v = ((const half8*)src)[i];
  c8v q;
#pragma unroll
  for (int j = 0; j < 8; ++j) q[j] = q8_val((float)v[j], s);
  ((c8v*)out)[i] = q;
}

// attention output: strided read of Q slice of qkv buffer -> dense int8
__global__ void quant_strided8_k(const f16* __restrict__ src,
                                 const unsigned* __restrict__ slot,
                                 int8_t* __restrict__ out) {
  int i = blockIdx.x * blockDim.x + threadIdx.x;  // 8-elem groups
  if (i >= NE_TOT / 8) return;
  int row = i / 96, c8 = i - row * 96;
  half8 v = *(const half8*)(src + (size_t)row * 2304 + c8 * 8);
  float s = slot_scale(slot);
  c8v q;
#pragma unroll
  for (int j = 0; j < 8; ++j) q[j] = q8_val((float)v[j], s);
  ((c8v*)out)[i] = q;
}

// ---------------------------------------------------------------- int8 GEMM
// C[m,n] = (sum_k qA[m,k]*qB[n,k]) * sA*sB + bias[n] (+resid) (+gelu).
// 128x128 tile, BK=64 (bytes), 4 waves of 64x64, mfma_i32_16x16x64_i8,
// global_load_lds width-16 staging. Exact integer dot products.
__global__ __launch_bounds__(256) void gemm_i8_k(
    const int8_t* __restrict__ A, const int8_t* __restrict__ B,
    const unsigned* __restrict__ slotA, const unsigned* __restrict__ slotB,
    const float* __restrict__ bias, const float* resid,
    float* outf, f16* outh, unsigned* spread, int slot,
    int N, int K, int gelu_mode) {
  __shared__ __attribute__((aligned(16))) int8_t sA[128 * 64];
  __shared__ __attribute__((aligned(16))) int8_t sB[128 * 64];
  int tid = threadIdx.x;
  int n0 = blockIdx.x * 128, m0 = blockIdx.y * 128;
  int lane = tid & 63, wv = tid >> 6;
  int wm = (wv & 1) * 64, wn = (wv >> 1) * 64;
  int lr = lane & 15, quad = lane >> 4;

  i32x4 acc[4][4];
#pragma unroll
  for (int i = 0; i < 4; ++i)
#pragma unroll
    for (int j = 0; j < 4; ++j) acc[i][j] = i32x4{0, 0, 0, 0};

  for (int k0 = 0; k0 < K; k0 += 64) {
#pragma unroll
    for (int it = 0; it < 2; ++it) {
      int c = it * 256 + tid;      // 512 chunks of 16B per tile
      int r = c >> 2, kc = c & 3;  // row, 16B column within the 64B row
      async_copy16(&sA[c * 16], A + (size_t)(m0 + r) * K + k0 + kc * 16);
      async_copy16(&sB[c * 16], B + (size_t)(n0 + r) * K + k0 + kc * 16);
    }
    __syncthreads();
    i32x4 af[4], bfv[4];
#pragma unroll
    for (int i = 0; i < 4; ++i)
      af[i] = *(const i32x4*)&sA[(wm + i * 16 + lr) * 64 + quad * 16];
#pragma unroll
    for (int j = 0; j < 4; ++j)
      bfv[j] = *(const i32x4*)&sB[(wn + j * 16 + lr) * 64 + quad * 16];
#pragma unroll
    for (int i = 0; i < 4; ++i)
#pragma unroll
      for (int j = 0; j < 4; ++j)
        acc[i][j] = __builtin_amdgcn_mfma_i32_16x16x64_i8(af[i], bfv[j],
                                                          acc[i][j], 0, 0, 0);
    __syncthreads();
  }

  float scale = slot_scale(slotA) * slot_scale(slotB);
  // epilogue: C/D layout col=lane&15, row=quad*4+reg
  float lmax = 0.f;
#pragma unroll
  for (int i = 0; i < 4; ++i) {
    int r0 = m0 + wm + i * 16 + quad * 4;
#pragma unroll
    for (int j = 0; j < 4; ++j) {
      int col = n0 + wn + j * 16 + lr;
      float bv = bias[col];
#pragma unroll
      for (int reg = 0; reg < 4; ++reg) {
        size_t idx = (size_t)(r0 + reg) * N + col;
        float v = (float)acc[i][j][reg] * scale + bv;
        if (resid) v += resid[idx];
        if (gelu_mode) {
          v = gelu_fast(v);
          lmax = fmaxf(lmax, fabsf(v));
        }
        if (outf) outf[idx] = v;
        else outh[idx] = (f16)v;
      }
    }
  }
  if (gelu_mode) {
    float bm = block_reduce_max(lmax);
    if (tid == 0)
      atomicMax(spread_cell(spread, slot, blockIdx.x + gridDim.x * blockIdx.y),
                __float_as_uint(bm));
  }
}

// ---------------------------------------------------------------- attention
// one block per (b,c,head). MFMA path: S = Q K^T (16x16x32 f16, wave = 16-row
// strip), register softmax (row lives on 16 lanes x 4 tiles), P -> LDS
// (C-layout -> A-layout transform), O = P V. O written over the Q slice.
__global__ __launch_bounds__(256) void attn_k(f16* __restrict__ qkv,
                                              unsigned* spread, int slot) {
  // stride 72 f16: rows stay 16B-aligned; ds_read_b128 fragments hit all 8
  // bank-phases evenly ((lr*9+quad)%8 uniform)
  __shared__ __attribute__((aligned(16))) f16 sQ[64 * 72];
  __shared__ __attribute__((aligned(16))) f16 sK[64 * 72];
  __shared__ __attribute__((aligned(16))) f16 sV[64 * 72];
  __shared__ __attribute__((aligned(16))) f16 sP[64 * 72];
  int tid = threadIdx.x, lane = tid & 63, wv = tid >> 6;
  int lr = lane & 15, quad = lane >> 4;
  int h = blockIdx.x % 12, bc = blockIdx.x / 12;
  size_t base = (size_t)bc * 64 * 2304;
  int qo = h * 64, ko = qo + 768, vo = qo + 1536;

#pragma unroll
  for (int p = 0; p < 2; ++p) {
    int idx = p * 256 + tid;     // 512 chunks of 8 f16
    int t = idx >> 3, d8 = idx & 7;
    size_t g = base + (size_t)t * 2304 + d8 * 8;
    *(half8*)&sQ[t * 72 + d8 * 8] = *(const half8*)(qkv + g + qo);
    *(half8*)&sK[t * 72 + d8 * 8] = *(const half8*)(qkv + g + ko);
    *(half8*)&sV[t * 72 + d8 * 8] = *(const half8*)(qkv + g + vo);
  }
  __syncthreads();

  // S = Q K^T: wave wv owns rows wv*16 .. wv*16+15; 4 col tiles j
  f32x4 acc[4];
#pragma unroll
  for (int j = 0; j < 4; ++j) acc[j] = f32x4{0.f, 0.f, 0.f, 0.f};
#pragma unroll
  for (int ks = 0; ks < 2; ++ks) {
    half8 aq = *(const half8*)&sQ[(wv * 16 + lr) * 72 + ks * 32 + quad * 8];
#pragma unroll
    for (int j = 0; j < 4; ++j) {
      half8 bk = *(const half8*)&sK[(j * 16 + lr) * 72 + ks * 32 + quad * 8];
      acc[j] = __builtin_amdgcn_mfma_f32_16x16x32_f16(aq, bk, acc[j], 0, 0, 0);
    }
  }

  // softmax: row (quad,reg) spans 16 lanes (lr) x 4 tiles (j)
  float pr[4][4];  // [j][reg]
#pragma unroll
  for (int reg = 0; reg < 4; ++reg) {
    float v0 = acc[0][reg] * 0.125f, v1 = acc[1][reg] * 0.125f;
    float v2 = acc[2][reg] * 0.125f, v3 = acc[3][reg] * 0.125f;
    float mx = fmaxf(fmaxf(v0, v1), fmaxf(v2, v3));
    for (int o = 8; o; o >>= 1) mx = fmaxf(mx, __shfl_xor(mx, o));
    float e0 = __expf(v0 - mx), e1 = __expf(v1 - mx);
    float e2 = __expf(v2 - mx), e3 = __expf(v3 - mx);
    float sum = e0 + e1 + e2 + e3;
    for (int o = 8; o; o >>= 1) sum += __shfl_xor(sum, o);
    float inv = 1.f / sum;
    pr[0][reg] = e0 * inv; pr[1][reg] = e1 * inv;
    pr[2][reg] = e2 * inv; pr[3][reg] = e3 * inv;
  }
  // P: C-layout -> natural row-major in LDS (scalar b16, ~2-way conflicts)
#pragma unroll
  for (int j = 0; j < 4; ++j)
#pragma unroll
    for (int reg = 0; reg < 4; ++reg)
      sP[(wv * 16 + quad * 4 + reg) * 72 + j * 16 + lr] = (f16)pr[j][reg];
  __syncthreads();

  // O = P V: A from sP rows (vector), B = V[s][d] column reads (scalar u16)
  f32x4 oacc[4];
#pragma unroll
  for (int j = 0; j < 4; ++j) oacc[j] = f32x4{0.f, 0.f, 0.f, 0.f};
#pragma unroll
  for (int ks = 0; ks < 2; ++ks) {
    half8 ap = *(const half8*)&sP[(wv * 16 + lr) * 72 + ks * 32 + quad * 8];
#pragma unroll
    for (int j = 0; j < 4; ++j) {
      half8 bv;
#pragma unroll
      for (int jj = 0; jj < 8; ++jj)
        bv[jj] = sV[(ks * 32 + quad * 8 + jj) * 72 + j * 16 + lr];
      oacc[j] = __builtin_amdgcn_mfma_f32_16x16x32_f16(ap, bv, oacc[j], 0, 0, 0);
    }
  }

  float lmax = 0.f;
#pragma unroll
  for (int j = 0; j < 4; ++j)
#pragma unroll
    for (int reg = 0; reg < 4; ++reg) {
      int m = wv * 16 + quad * 4 + reg;
      float v = oacc[j][reg];
      qkv[base + (size_t)m * 2304 + qo + j * 16 + lr] = (f16)v;
      lmax = fmaxf(lmax, fabsf(v));
    }
  lmax = block_reduce_max(lmax);
  if (tid == 0)
    atomicMax(spread_cell(spread, slot, blockIdx.x), __float_as_uint(lmax));
}

// ---------------------------------------------------------------- launch

extern "C" void kernel_launch(void* const* d_in, const int* in_sizes, int n_in,
                              void* d_out, int out_size, void* d_ws,
                              size_t ws_size, hipStream_t stream) {
  (void)in_sizes; (void)n_in; (void)out_size; (void)ws_size;
  const float* x      = (const float*)d_in[0];
  const float* ln1_g  = (const float*)d_in[1];
  const float* ln1_b  = (const float*)d_in[2];
  const float* qkv_w  = (const float*)d_in[3];
  const float* qkv_b  = (const float*)d_in[4];
  const float* proj_w = (const float*)d_in[5];
  const float* proj_b = (const float*)d_in[6];
  const float* ln2_g  = (const float*)d_in[7];
  const float* ln2_b  = (const float*)d_in[8];
  const float* fc1_w  = (const float*)d_in[9];
  const float* fc1_b  = (const float*)d_in[10];
  const float* fc2_w  = (const float*)d_in[11];
  const float* fc2_b  = (const float*)d_in[12];
  float* out = (float*)d_out;

  char* ws = (char*)d_ws;
  unsigned* spread = (unsigned*)ws;                       // 8 x 64 cells x 64B
  unsigned* finals = (unsigned*)(ws + 8 * 64 * SPREAD_STRIDE * 4);
  int8_t* qkv_wq  = (int8_t*)(ws + 33280);                // int8 weights
  int8_t* proj_wq = qkv_wq + 1769472;
  int8_t* fc1_wq  = proj_wq + 589824;
  int8_t* fc2_wq  = fc1_wq + 2359296;
  // g_q region (96 MB) also hosts hbuf (f16, 48 MB) + a_i8 (24 MB): both are
  // dead by the time g_q is written (after fc1).
  int8_t* g_q  = fc2_wq + 2359296;
  f16*    hbuf = (f16*)g_q;                               // LN y (f16)
  int8_t* a_i8 = g_q + 50331648;                          // quantized acts
  f16*    big  = (f16*)(g_q + 100663296);                 // qkv / gelu f16
  // total ws use ~309 MB

  zero_spread_k<<<(8 * 64 * SPREAD_STRIDE + 255) / 256, 256, 0, stream>>>(spread);

  absmax_k<<<256, 256, 0, stream>>>(qkv_w, 1769472 / 4, spread, 1);
  absmax_k<<<256, 256, 0, stream>>>(proj_w, 589824 / 4, spread, 2);
  absmax_k<<<256, 256, 0, stream>>>(fc1_w, 2359296 / 4, spread, 3);
  absmax_k<<<256, 256, 0, stream>>>(fc2_w, 2359296 / 4, spread, 4);
  reduce_slots_k<<<1, 256, 0, stream>>>(spread, finals, 1, 4);
  quant_w8_k<<<(1769472 / 4 + 255) / 256, 256, 0, stream>>>(qkv_w, 1769472 / 4, finals + 1, qkv_wq);
  quant_w8_k<<<(589824 / 4 + 255) / 256, 256, 0, stream>>>(proj_w, 589824 / 4, finals + 2, proj_wq);
  quant_w8_k<<<(2359296 / 4 + 255) / 256, 256, 0, stream>>>(fc1_w, 2359296 / 4, finals + 3, fc1_wq);
  quant_w8_k<<<(2359296 / 4 + 255) / 256, 256, 0, stream>>>(fc2_w, 2359296 / 4, finals + 4, fc2_wq);

  // LN1 -> hbuf (f16) + absmax; quantize -> a_i8
  ln_k<<<32768, 256, 0, stream>>>(x, ln1_g, ln1_b, hbuf, spread, 0);
  reduce_slots_k<<<1, 64, 0, stream>>>(spread, finals, 0, 1);
  quant8_k<<<NE_TOT / 8 / 256, 256, 0, stream>>>(hbuf, NE_TOT / 8, finals + 0, a_i8);
  // qkv = dequant(a_q @ qkv_wq^T) + b -> big (f16)
  gemm_i8_k<<<dim3(18, 256), 256, 0, stream>>>(a_i8, qkv_wq, finals + 0, finals + 1,
                                               qkv_b, nullptr, nullptr, big,
                                               nullptr, 0, 2304, 768, 0);
  // attention in place (o -> Q slice of big)
  attn_k<<<6144, 256, 0, stream>>>(big, spread, 5);
  reduce_slots_k<<<1, 64, 0, stream>>>(spread, finals, 5, 1);
  // fq(o) -> a_i8
  quant_strided8_k<<<NE_TOT / 8 / 256, 256, 0, stream>>>(big, finals + 5, a_i8);
  // x2 = o_q @ proj_wq^T + b + x -> out
  gemm_i8_k<<<dim3(6, 256), 256, 0, stream>>>(a_i8, proj_wq, finals + 5, finals + 2,
                                              proj_b, x, out, nullptr,
                                              nullptr, 0, 768, 768, 0);
  // LN2 -> hbuf + absmax; quantize -> a_i8
  ln_k<<<32768, 256, 0, stream>>>(out, ln2_g, ln2_b, hbuf, spread, 6);
  reduce_slots_k<<<1, 64, 0, stream>>>(spread, finals, 6, 1);
  quant8_k<<<NE_TOT / 8 / 256, 256, 0, stream>>>(hbuf, NE_TOT / 8, finals + 6, a_i8);
  // g = gelu(h_q @ fc1_wq^T + b) -> big (f16) + absmax
  gemm_i8_k<<<dim3(24, 256), 256, 0, stream>>>(a_i8, fc1_wq, finals + 6, finals + 3,
                                               fc1_b, nullptr, nullptr, big,
                                               spread, 7, 3072, 768, 1);
  reduce_slots_k<<<1, 64, 0, stream>>>(spread, finals, 7, 1);
  // fq(g) -> g_q (int8; overwrites dead hbuf/a_i8)
  quant8_k<<<100663296 / 8 / 256, 256, 0, stream>>>(big, 100663296 / 8, finals + 7, g_q);
  // out = g_q @ fc2_wq^T + b + x2 (in-place residual)
  gemm_i8_k<<<dim3(6, 256), 256, 0, stream>>>(g_q, fc2_wq, finals + 7, finals + 4,
                                              fc2_b, out, out, nullptr,
                                              nullptr, 0, 768, 3072, 0);
}